// Round 4
// baseline (872.805 us; speedup 1.0000x reference)
//
#include <hip/hip_runtime.h>
#include <cfloat>

// ---- problem dims ----
#define NN    16380
#define RR    819
#define APR   20
#define KNB   16
#define HID   64
#define LAYERS 6
#define BINS  100
#define N64   (NN*HID)

// ---- geometry ----
#define ATB   32
#define NBLK  512               // 512*32 = 16384 >= NN
#define LDA   68
#define LDB   72                // u16 row stride for bf16 A-matrices (144B, 16B-aligned)
#define CSIZE 4.375f            // 70/16

// ---- workspace float offsets ----
#define OFF_QA    0
#define OFF_KA    (1*N64)
#define OFF_FA    (2*N64)
#define OFF_QB    (3*N64)
#define OFF_KB    (4*N64)
#define OFF_FB    (5*N64)
#define OFF_VA    (6*N64)           // 3 planes
#define OFF_VB    (9*N64)           // 3 planes
#define OFF_S     (12*N64)
#define OFF_DIRNS (13*N64)          // N*48 (sorted space)
#define OFF_C4    (OFF_DIRNS + NN*48)
#define OFF_C4S   (OFF_C4 + NN*4)
#define OFF_RES   (OFF_C4S + NN*4)
#define OFF_NBRS  (OFF_RES + RR*64)    // int N*16 (sorted space)
#define OFF_BINSS (OFF_NBRS + NN*16)   // int N*16
#define OFF_O2N   (OFF_BINSS + NN*16)  // int N
#define OFF_N2O   (OFF_O2N + NN)       // int N
#define OFF_CELL  (OFF_N2O + NN)       // int N
#define OFF_HIST  (OFF_CELL + NN)      // int 4096
#define OFF_CNT   (OFF_HIST + 4096)    // int 4096 (adjacent: one memset covers both)
#define OFF_BASE  (OFF_CNT + 4096)     // int 4096

typedef unsigned long long u64;
typedef unsigned short ushort_t;
#define U64MAX 0xFFFFFFFFFFFFFFFFull

using short8 = __attribute__((ext_vector_type(8))) short;
using f32x4  = __attribute__((ext_vector_type(4))) float;

__device__ __forceinline__ float gelu_f(float x) {
    float x3 = x*x*x;
    float t = tanhf(0.7978845608028654f*(x + 0.044715f*x3));
    return 0.5f*x*(1.0f+t);
}
__device__ __forceinline__ float sigmoid_f(float x) {
    return 1.0f/(1.0f + expf(-x));
}
__device__ __forceinline__ int spread3(int x) {   // 4-bit -> every 3rd bit
    return (x&1) | ((x&2)<<2) | ((x&4)<<4) | ((x&8)<<6);
}
__device__ __forceinline__ unsigned sortable_u32(float f) {
    unsigned u = __float_as_uint(f);
    return u ^ ((u & 0x80000000u) ? 0xFFFFFFFFu : 0x80000000u);
}
// bf16 pack/unpack (RNE)
__device__ __forceinline__ unsigned short f2bf(float x) {
    unsigned u = __float_as_uint(x);
    u += 0x7fff + ((u >> 16) & 1);
    return (unsigned short)(u >> 16);
}
__device__ __forceinline__ float bf2f(unsigned short h) {
    return __uint_as_float(((unsigned)h) << 16);
}

// ---------------- fused pad + cell-id + histogram + resb zero ----------------
__global__ void pad_cell_kernel(const float* __restrict__ coords, float4* __restrict__ c4,
                                int* __restrict__ cellid, int* __restrict__ hist,
                                float* __restrict__ resb, int n) {
    int i = blockIdx.x*256 + threadIdx.x;
    for (int j = i; j < RR*HID; j += 16384) resb[j] = 0.f;
    if (i >= n) return;
    float x = coords[3*i], y = coords[3*i+1], z = coords[3*i+2];
    float sq = __fadd_rn(__fadd_rn(__fmul_rn(x,x), __fmul_rn(y,y)), __fmul_rn(z,z));
    c4[i] = make_float4(x, y, z, sq);
    int cx = min(15, max(0, (int)(x * (16.0f/70.0f))));
    int cy = min(15, max(0, (int)(y * (16.0f/70.0f))));
    int cz = min(15, max(0, (int)(z * (16.0f/70.0f))));
    int m = spread3(cx) | (spread3(cy)<<1) | (spread3(cz)<<2);
    cellid[i] = m;
    atomicAdd(&hist[m], 1);
}
__global__ void scan_kernel(const int* __restrict__ hist, int* __restrict__ base) {
    __shared__ int part[256];
    int t = threadIdx.x;
    int loc[16]; int s = 0;
    #pragma unroll
    for (int e = 0; e < 16; ++e) { loc[e] = s; s += hist[t*16+e]; }
    part[t] = s;
    __syncthreads();
    if (t == 0) { int acc = 0; for (int i = 0; i < 256; ++i) { int v = part[i]; part[i] = acc; acc += v; } }
    __syncthreads();
    int off = part[t];
    #pragma unroll
    for (int e = 0; e < 16; ++e) base[t*16+e] = off + loc[e];
}
__global__ void scatter_kernel(const int* __restrict__ cellid, const int* __restrict__ base,
                               int* __restrict__ cnt, int* __restrict__ o2n,
                               int* __restrict__ n2o, const float4* __restrict__ c4,
                               float4* __restrict__ c4s, int n) {
    int i = blockIdx.x*256 + threadIdx.x;
    if (i >= n) return;
    int m = cellid[i];
    int pos = base[m] + atomicAdd(&cnt[m], 1);
    o2n[i] = pos; n2o[pos] = i;
    c4s[pos] = c4[i];
}

// ---------------- grid kNN (round-16 verbatim: R=1 early-exit) ----------------
#define SCRATCH 1024
__global__ __launch_bounds__(256) void knn_grid_kernel(
    const float4* __restrict__ c4s, const int* __restrict__ base, const int* __restrict__ hist,
    const int* __restrict__ n2o, const int* __restrict__ o2n,
    int* __restrict__ nbr, int* __restrict__ binsO, float* __restrict__ dirn, int n)
{
    __shared__ int sIdx[4][SCRATCH];
    int tid = threadIdx.x;
    int wv = tid >> 6, lane = tid & 63;
    int i = blockIdx.x*4 + wv;
    bool valid = i < n;
    int ii = valid ? i : 0;
    float4 cd = c4s[ii];
    float sqd = cd.w;
    int cx = min(15, max(0, (int)(cd.x * (16.0f/70.0f))));
    int cy = min(15, max(0, (int)(cd.y * (16.0f/70.0f))));
    int cz = min(15, max(0, (int)(cd.z * (16.0f/70.0f))));
    u64 dlist = U64MAX;
    u64 vmax  = U64MAX;
    int* sidx = sIdx[wv];

    auto compute_pk = [&](int idx) -> u64 {
        if (idx == i) return U64MAX;
        float4 cc = c4s[idx];
        float dt = __fmul_rn(cd.x, cc.x);
        dt = __fmaf_rn(cd.y, cc.y, dt);
        dt = __fmaf_rn(cd.z, cc.z, dt);
        float key = __fsub_rn(__fadd_rn(sqd, cc.w), __fmul_rn(2.0f, dt));
        int org = n2o[idx];
        return ((u64)sortable_u32(key) << 32) | (unsigned)org;
    };

    auto process_batch = [&](int M) {
        if (M <= 0) return;
        u64 lmin = U64MAX;
        for (int p = lane; p < M; p += 64) {
            u64 pk = compute_pk(sidx[p]);
            lmin = (pk < lmin) ? pk : lmin;
        }
        u64 T = lmin;
        #pragma unroll
        for (int off = 1; off < 64; off <<= 1) {
            u64 o = __shfl_xor(T, off);
            T = (o > T) ? o : T;
        }
        for (int c0 = 0; c0 < M; c0 += 64) {
            int p = c0 + lane;
            u64 mypk = (p < M) ? compute_pk(sidx[p]) : U64MAX;
            u64 bound = (vmax < T) ? vmax : T;
            unsigned long long mask = __ballot(mypk <= bound);
            while (mask) {
                int lb = (int)__builtin_ctzll(mask);
                mask &= mask - 1;
                u64 dc = __shfl(mypk, lb);
                if (dc < vmax) {
                    u64 dp = __shfl_up(dlist, 1);
                    bool below = dc < dlist;
                    bool take  = below && (lane == 0 || dc >= dp);
                    if (lane < 16) dlist = below ? (take ? dc : dp) : dlist;
                    vmax = __shfl(dlist, 15);
                }
            }
        }
    };

    for (int R = 1; R <= 16; ++R) {
        int side = 2*R+1;
        int ncell = side*side*side;
        int M = 0;
        for (int t0 = 0; t0 < ncell; t0 += 64) {
            int t = t0 + lane;
            int cnt = 0, b = 0;
            if (t < ncell) {
                int dxc = t % side - R;
                int dyc = (t/side) % side - R;
                int dzc = t/(side*side) - R;
                int ch = max(abs(dxc), max(abs(dyc), abs(dzc)));
                bool use = (R == 1) || (ch == R);
                int x = cx+dxc, y = cy+dyc, z = cz+dzc;
                if (use && x>=0 && x<16 && y>=0 && y<16 && z>=0 && z<16) {
                    int m = spread3(x) | (spread3(y)<<1) | (spread3(z)<<2);
                    cnt = hist[m]; b = base[m];
                }
            }
            int incl = cnt;
            #pragma unroll
            for (int o = 1; o < 64; o <<= 1) { int v = __shfl_up(incl, o); if (lane >= o) incl += v; }
            int excl = incl - cnt;
            int tot = __shfl(incl, 63);
            if (M + tot > SCRATCH) { process_batch(M); M = 0; }
            for (int e = 0; e < cnt; ++e) {
                int pos = M + excl + e;
                if (pos < SCRATCH) sidx[pos] = b + e;
            }
            M = min(M + tot, SCRATCH);
        }
        process_batch(M);
        float rim = (float)R * CSIZE;
        unsigned thS = sortable_u32(rim*rim - 0.05f);
        if ((unsigned)(vmax >> 32) < thS) break;
    }
    if (valid && lane < 16) {
        int org = (int)(dlist & 0xFFFFFFFFull);
        int src = o2n[org];
        float4 cs = c4s[src];
        float dx = __fsub_rn(cd.x, cs.x);
        float dy = __fsub_rn(cd.y, cs.y);
        float dz = __fsub_rn(cd.z, cs.z);
        float ss = __fadd_rn(__fadd_rn(__fmul_rn(dx,dx), __fmul_rn(dy,dy)),
                             __fmul_rn(dz,dz));
        float dd = __fsqrt_rn(__fadd_rn(ss, 1e-12f));
        nbr[i*KNB + lane] = src;
        float bf = __fmul_rn(__fdiv_rn(dd, 10.0f), 100.0f);
        int b = (int)bf;
        b = min(max(b, 0), BINS-1);
        binsO[i*KNB + lane] = b;
        dirn[i*48 + lane*3 + 0] = __fdiv_rn(dx, dd);
        dirn[i*48 + lane*3 + 1] = __fdiv_rn(dy, dd);
        dirn[i*48 + lane*3 + 2] = __fdiv_rn(dz, dd);
    }
}

// ---------------- prologue: unchanged fp32 (256 threads, 2 rows/thread) ----------------
__global__ __launch_bounds__(256) void prologue_kernel(
    const int* __restrict__ aid, const int* __restrict__ rid, const int* __restrict__ eid,
    const int* __restrict__ n2o,
    const float* __restrict__ ea, const float* __restrict__ er, const float* __restrict__ ee,
    const float* __restrict__ Win, const float* __restrict__ Wq, const float* __restrict__ Wk,
    const float* __restrict__ Wv,
    float* __restrict__ sg, float* __restrict__ qout, float* __restrict__ kout,
    float* __restrict__ vfout)
{
    __shared__ __align__(16) float sS[ATB*LDA];
    __shared__ __align__(16) float sH[ATB*LDA];
    __shared__ __align__(16) float sW[4096];
    const int tid = threadIdx.x;
    const int a0 = blockIdx.x*ATB;
    const int gi = tid>>4, gj = tid&15;
    const int lrow = tid>>3, lsub = tid&7;

    auto stageW = [&](const float* W) {
        const float4* src = (const float4*)W; float4* dst = (float4*)sW;
        #pragma unroll
        for (int r = 0; r < 4; ++r) dst[tid + 256*r] = src[tid + 256*r];
    };
    auto do_gemm = [&](const float* sA, float4& c0, float4& c1) {
        const float* a0p = sA + gi*LDA;
        const float* a1p = sA + (gi+16)*LDA;
        const float* wr  = sW + gj*4;
        #pragma unroll 8
        for (int k = 0; k < 64; ++k) {
            float av0 = a0p[k], av1 = a1p[k];
            float4 w = *(const float4*)(wr + k*64);
            c0.x = fmaf(av0,w.x,c0.x); c0.y = fmaf(av0,w.y,c0.y);
            c0.z = fmaf(av0,w.z,c0.z); c0.w = fmaf(av0,w.w,c0.w);
            c1.x = fmaf(av1,w.x,c1.x); c1.y = fmaf(av1,w.y,c1.y);
            c1.z = fmaf(av1,w.z,c1.z); c1.w = fmaf(av1,w.w,c1.w);
        }
    };
    auto do_ln = [&](const float* src, float* dst) {
        const float* sp = src + lrow*LDA + lsub*8;
        float v[8]; float s1 = 0.f;
        #pragma unroll
        for (int e = 0; e < 8; ++e) { v[e] = sp[e]; s1 += v[e]; }
        s1 += __shfl_xor(s1,1); s1 += __shfl_xor(s1,2); s1 += __shfl_xor(s1,4);
        float mean = s1*(1.0f/64.0f);
        float s2 = 0.f;
        #pragma unroll
        for (int e = 0; e < 8; ++e) { float t = v[e]-mean; s2 += t*t; }
        s2 += __shfl_xor(s2,1); s2 += __shfl_xor(s2,2); s2 += __shfl_xor(s2,4);
        float sc = 1.0f/sqrtf(s2*(1.0f/64.0f)+1e-5f);
        float* dp = dst + lrow*LDA + lsub*8;
        #pragma unroll
        for (int e = 0; e < 8; ++e) dp[e] = (v[e]-mean)*sc;
    };
    auto store_g = [&](float* base, float4 c0, float4 c1) {
        int g0 = a0+gi, g1 = a0+gi+16;
        if (g0 < NN) *(float4*)(base + (size_t)g0*64 + gj*4) = c0;
        if (g1 < NN) *(float4*)(base + (size_t)g1*64 + gj*4) = c1;
    };

    {   // feat -> sH  (overlapped with Win staging; both guarded by next sync)
        int ga = a0 + lrow;
        int io = (ga < NN) ? n2o[ga] : 0;
        #pragma unroll
        for (int e = 0; e < 8; ++e) {
            int c = lsub*8 + e;
            float x = 0.f;
            if (ga < NN) {
                if (c < 32)      x = ea[aid[io]*32 + c];
                else if (c < 48) x = er[rid[io]*16 + (c-32)];
                else             x = ee[eid[io]*16 + (c-48)];
            }
            sH[lrow*LDA + c] = x;
        }
    }
    stageW(Win);
    __syncthreads();
    {
        float4 c0 = make_float4(0,0,0,0), c1 = c0;
        do_gemm(sH, c0, c1);
        *(float4*)(sS + gi*LDA + gj*4)      = c0;
        *(float4*)(sS + (gi+16)*LDA + gj*4) = c1;
        store_g(sg, c0, c1);
    }
    __syncthreads();
    do_ln(sS, sH);
    stageW(Wk);
    __syncthreads();
    { float4 c0 = make_float4(0,0,0,0), c1 = c0; do_gemm(sH, c0, c1); store_g(kout, c0, c1); }
    __syncthreads();
    stageW(Wv); __syncthreads();
    { float4 c0 = make_float4(0,0,0,0), c1 = c0; do_gemm(sH, c0, c1); store_g(vfout, c0, c1); }
    __syncthreads();
    stageW(Wq); __syncthreads();
    { float4 c0 = make_float4(0,0,0,0), c1 = c0; do_gemm(sH, c0, c1); store_g(qout, c0, c1); }
}

// ---------------- fused layer kernel: MFMA split-bf16 for the 8 clean GEMMs ----------------
// Round-4: fp32 VALU GEMMs were the invariant ~40us/layer across all geometries
// (MfmaUtil 0 throughout). Wo/W1x2/W2x2/Wk/Wv/Wq now run on the matrix pipe as
// 16x16x32 bf16 MFMA with hi/lo split operands (3 MFMAs/tile: Ah*Bh+Al*Bh+Ah*Bl,
// products exact to ~2^-16 rel -> absmax should stay ~0.024). Weights are packed
// fp32->split-bf16 during LDS staging (k-group-major [kg][n][e], 16B/lane frags).
// A-matrices (LN out, attn msg, FFN mid) stored as bf16 hi/lo pairs in LDS.
// Wg + 3x Wvec stay fp32 VALU (outputs consumed in (row,4col) mapping).
// K-permutation invariance: any k relabeling applied to BOTH A and B packs
// cancels in the dot product, so only lane<->(row/col) mapping matters.
__global__ __launch_bounds__(512, 2) void layer_kernel(
    const float* __restrict__ qin, const float* __restrict__ kin, const float* __restrict__ vfin,
    float* __restrict__ qout, float* __restrict__ kout, float* __restrict__ vfout,
    const float* __restrict__ vin, float* __restrict__ vout,
    float* __restrict__ sg, const float* __restrict__ dirn,
    const int* __restrict__ nbr, const int* __restrict__ bins,
    float* __restrict__ resb, const int* __restrict__ ridx, const int* __restrict__ n2o,
    const float* __restrict__ Wvec, const float* __restrict__ wdir,
    const float* __restrict__ dist_bias,
    const float* __restrict__ Wo, const float* __restrict__ W1, const float* __restrict__ W2,
    const float* __restrict__ Wg, const float* __restrict__ Wq, const float* __restrict__ Wk,
    const float* __restrict__ Wv, int l)
{
    __shared__ __align__(16) float sS[ATB*LDA];            // fp32 residual
    __shared__ __align__(16) float sVA[3][ATB*LDA];        // fp32 vector aggregates
    __shared__ __align__(16) unsigned short sHh[ATB*LDB];  // LN out hi
    __shared__ __align__(16) unsigned short sHl[ATB*LDB];  // LN out lo
    __shared__ __align__(16) unsigned short sMh[ATB*LDB];  // msg / FFN-mid hi
    __shared__ __align__(16) unsigned short sMl[ATB*LDB];  // msg / FFN-mid lo
    __shared__ __align__(16) float sW[4096];               // fp32 weight OR packed bf16 h(0..8KB)+l(8..16KB)
    __shared__ float sDS[ATB*24];
    // total: 8704+26112+4608*4+16384+3072 = 72704 B -> 2 blocks/CU

    const int tid = threadIdx.x;
    const int bswz = (blockIdx.x & 7) * (NBLK/8) + (blockIdx.x >> 3);
    const int a0 = bswz*ATB;
    const int gi = tid>>4, gj = tid&15;       // (row, 4-col) mapping for VALU phases
    const int wv = tid>>6, lane = tid&63;     // wave/lane
    const int lr = lane & 15, lgp = lane >> 4;
    const int mt = wv >> 2, ntt = wv & 3;     // 2 M-tiles x 4 N-tiles
    const int crow0 = mt*16 + lgp*4;          // C-frag rows (verified C/D map)
    const int ccol  = ntt*16 + lr;            // C-frag col

    const float* Wo_l = Wo + l*4096;
    const float* Wg_l = Wg + l*4096;
    const float* Wc_l = Wvec + l*4096;
    const float* W1_l = W1 + l*8192;
    const float* W2_l = W2 + l*8192;
    const float* db_l = dist_bias + l*BINS*8;
    const float* wd_l = wdir + l*64;

    // fp32 weight staging (for Wg / Wvec VALU GEMMs)
    auto stageW = [&](const float* W) {
        const float4* src = (const float4*)W; float4* dst = (float4*)sW;
        dst[tid]       = src[tid];
        dst[tid + 512] = src[tid + 512];
    };
    // packed split-bf16 weight staging: B[k][n] (k=0..63 rows of length 64, row
    // stride `stride` floats) -> hi at sW[kg*512 + n*8 + (k&7)], lo at +4096 u16.
    auto stagePK = [&](const float* Wsrc, int stride) {
        int k  = tid >> 3;                 // each thread: one k-row, 8 n's
        int n0 = (tid & 7) * 8;
        const float* row = Wsrc + (size_t)k*stride + n0;
        float4 w0 = *(const float4*)(row);
        float4 w1 = *(const float4*)(row + 4);
        unsigned short* ph = (unsigned short*)sW;
        unsigned short* pl = ph + 4096;
        int base = (k >> 3)*512 + n0*8 + (k & 7);
        float vv[8] = {w0.x,w0.y,w0.z,w0.w,w1.x,w1.y,w1.z,w1.w};
        #pragma unroll
        for (int j = 0; j < 8; ++j) {
            unsigned short h = f2bf(vv[j]);
            ph[base + j*8] = h;
            pl[base + j*8] = f2bf(vv[j] - bf2f(h));
        }
    };
    // MFMA GEMM: C(32x64) = A(32x64) * B(64x64), A in split-bf16 LDS [32][LDB],
    // B packed in sW. 3-term split per k-tile.
    auto mfma_gemm = [&](const unsigned short* Ah, const unsigned short* Al, f32x4& acc) {
        const unsigned short* pw = (const unsigned short*)sW;
        #pragma unroll
        for (int kt = 0; kt < 2; ++kt) {
            int aoff = (mt*16 + lr)*LDB + kt*32 + lgp*8;
            short8 ah = *(const short8*)(Ah + aoff);
            short8 al = *(const short8*)(Al + aoff);
            int boff = (kt*4 + lgp)*512 + (ntt*16 + lr)*8;
            short8 bh = *(const short8*)(pw + boff);
            short8 bl = *(const short8*)(pw + 4096 + boff);
            acc = __builtin_amdgcn_mfma_f32_16x16x32_bf16(ah, bh, acc, 0, 0, 0);
            acc = __builtin_amdgcn_mfma_f32_16x16x32_bf16(al, bh, acc, 0, 0, 0);
            acc = __builtin_amdgcn_mfma_f32_16x16x32_bf16(ah, bl, acc, 0, 0, 0);
        }
    };
    auto addToS = [&](const f32x4& a) {        // sS += C-frag (unique addr per lane)
        #pragma unroll
        for (int r = 0; r < 4; ++r) sS[(crow0+r)*LDA + ccol] += a[r];
    };
    auto storeG2 = [&](float* base, const f32x4& a) {
        #pragma unroll
        for (int r = 0; r < 4; ++r) {
            int g = a0 + crow0 + r;
            if (g < NN) base[(size_t)g*64 + ccol] = a[r];
        }
    };
    auto storeMid = [&](const f32x4& a) {      // post-gelu FFN mid -> sM split
        #pragma unroll
        for (int r = 0; r < 4; ++r) {
            int ob = (crow0+r)*LDB + ccol;
            unsigned short h = f2bf(a[r]);
            sMh[ob] = h; sMl[ob] = f2bf(a[r] - bf2f(h));
        }
    };
    // fp32 GEMM (Wvec): old mapping, 1 float4 out/thread
    auto do_gemm = [&](const float* sA, float4& c0) {
        const float* ap = sA + gi*LDA;
        const float* wr = sW + gj*4;
        #pragma unroll 8
        for (int k = 0; k < 64; ++k) {
            float av = ap[k];
            float4 w = *(const float4*)(wr + k*64);
            c0.x = fmaf(av,w.x,c0.x); c0.y = fmaf(av,w.y,c0.y);
            c0.z = fmaf(av,w.z,c0.z); c0.w = fmaf(av,w.w,c0.w);
        }
    };
    // fp32 GEMM reading split-bf16 A (for Wg gate)
    auto gemm_split = [&](const unsigned short* Ah, const unsigned short* Al, float4& c0) {
        const unsigned short* hh = Ah + gi*LDB;
        const unsigned short* hl = Al + gi*LDB;
        const float* wr = sW + gj*4;
        #pragma unroll
        for (int kb = 0; kb < 8; ++kb) {
            short8 vh = *(const short8*)(hh + kb*8);
            short8 vl = *(const short8*)(hl + kb*8);
            #pragma unroll
            for (int e = 0; e < 8; ++e) {
                float av = bf2f((unsigned short)vh[e]) + bf2f((unsigned short)vl[e]);
                float4 w = *(const float4*)(wr + (kb*8+e)*64);
                c0.x = fmaf(av,w.x,c0.x); c0.y = fmaf(av,w.y,c0.y);
                c0.z = fmaf(av,w.z,c0.z); c0.w = fmaf(av,w.w,c0.w);
            }
        }
    };
    // LN(sS) -> split-bf16 sH
    auto ln_split = [&]() {
        const float* sp = sS + gi*LDA + gj*4;
        float v[4]; float s1 = 0.f;
        #pragma unroll
        for (int e = 0; e < 4; ++e) { v[e] = sp[e]; s1 += v[e]; }
        s1 += __shfl_xor(s1,1); s1 += __shfl_xor(s1,2);
        s1 += __shfl_xor(s1,4); s1 += __shfl_xor(s1,8);
        float mean = s1*(1.0f/64.0f);
        float s2 = 0.f;
        #pragma unroll
        for (int e = 0; e < 4; ++e) { float t = v[e]-mean; s2 += t*t; }
        s2 += __shfl_xor(s2,1); s2 += __shfl_xor(s2,2);
        s2 += __shfl_xor(s2,4); s2 += __shfl_xor(s2,8);
        float sc = 1.0f/sqrtf(s2*(1.0f/64.0f)+1e-5f);
        int ob = gi*LDB + gj*4;
        #pragma unroll
        for (int e = 0; e < 4; ++e) {
            float y = (v[e]-mean)*sc;
            unsigned short h = f2bf(y);
            sHh[ob+e] = h; sHl[ob+e] = f2bf(y - bf2f(h));
        }
    };

    // ---- P0: load s + prestage packed Wo (sW idle during attention) ----
    {
        int ga = a0 + gi;
        float4 x = make_float4(0,0,0,0);
        if (ga < NN) x = ((const float4*)(sg + (size_t)ga*64))[gj];
        ((float4*)(sS + gi*LDA))[gj] = x;
    }
    stagePK(Wo_l, 64);

    // ---- P1: attention (8 waves x 4 atoms); msg written as split-bf16 ----
    #pragma unroll 1
    for (int aa = 0; aa < 4; ++aa) {
        int la = wv*4 + aa;
        int ga = a0 + la;
        int gq = (ga < NN) ? ga : (NN-1);
        float qh = qin[(size_t)gq*64 + lane];
        float lg[KNB]; int nb[KNB];
        #pragma unroll
        for (int k = 0; k < KNB; ++k) {
            int j = nbr[gq*KNB + k];
            nb[k] = j;
            float t = qh * kin[(size_t)j*64 + lane];
            t += __shfl_xor(t,1); t += __shfl_xor(t,2); t += __shfl_xor(t,4);
            lg[k] = t*0.35355339059327373f + db_l[bins[gq*KNB+k]*8 + (lane>>3)];
        }
        float m = lg[0];
        #pragma unroll
        for (int k = 1; k < KNB; ++k) m = fmaxf(m, lg[k]);
        float ssum = 0.f;
        #pragma unroll
        for (int k = 0; k < KNB; ++k) { lg[k] = expf(lg[k]-m); ssum += lg[k]; }
        float inv = 1.0f/ssum;
        float mh=0.f, s0=0.f, s1=0.f, s2=0.f;
        if (l > 0) {
            float b0=0.f, b1=0.f, b2=0.f;
            #pragma unroll
            for (int k = 0; k < KNB; ++k) {
                float w = lg[k]*inv; int j = nb[k];
                mh += w * vfin[(size_t)j*64 + lane];
                b0 += w * vin[(size_t)j*64 + lane];
                b1 += w * vin[(size_t)N64 + (size_t)j*64 + lane];
                b2 += w * vin[2*(size_t)N64 + (size_t)j*64 + lane];
                s0 += w * dirn[gq*48 + k*3 + 0];
                s1 += w * dirn[gq*48 + k*3 + 1];
                s2 += w * dirn[gq*48 + k*3 + 2];
            }
            sVA[0][la*LDA + lane] = b0;
            sVA[1][la*LDA + lane] = b1;
            sVA[2][la*LDA + lane] = b2;
        } else {
            #pragma unroll
            for (int k = 0; k < KNB; ++k) {
                float w = lg[k]*inv; int j = nb[k];
                mh += w * vfin[(size_t)j*64 + lane];
                s0 += w * dirn[gq*48 + k*3 + 0];
                s1 += w * dirn[gq*48 + k*3 + 1];
                s2 += w * dirn[gq*48 + k*3 + 2];
            }
        }
        {
            unsigned short h = f2bf(mh);
            sMh[la*LDB + lane] = h;
            sMl[la*LDB + lane] = f2bf(mh - bf2f(h));
        }
        if ((lane & 7) == 0) {
            int hh = lane >> 3;
            sDS[la*24 + 0*8 + hh] = s0;
            sDS[la*24 + 1*8 + hh] = s1;
            sDS[la*24 + 2*8 + hh] = s2;
        }
    }
    __syncthreads();   // covers: P0 sS, attention sM/sVA/sDS, packed Wo

    // ---- P2: s += msg @ Wo  (MFMA) ----
    {
        f32x4 acc = {0.f,0.f,0.f,0.f};
        mfma_gemm(sMh, sMl, acc);
        addToS(acc);
    }
    __syncthreads();   // sS stable; done reading sW(Wo), sM

    // ---- P3: h2 = LN(s) -> split; stage Wg fp32 ----
    ln_split();
    stageW(Wg_l);
    __syncthreads();

    // ---- P4: gate (VALU, split-A) + vector update (VALU, sVA fp32) ----
    {
        float4 g0v = make_float4(0,0,0,0);
        gemm_split(sHh, sHl, g0v);
        g0v.x = sigmoid_f(g0v.x); g0v.y = sigmoid_f(g0v.y);
        g0v.z = sigmoid_f(g0v.z); g0v.w = sigmoid_f(g0v.w);
        __syncthreads();            // done reading sW(Wg)
        stageW(Wc_l); __syncthreads();

        float4 wd4 = *(const float4*)&wd_l[gj*4];
        const int gidx = a0 + gi;
        #pragma unroll
        for (int p = 0; p < 3; ++p) {
            float4 t0 = make_float4(0,0,0,0);
            if (l > 0) do_gemm(sVA[p], t0);
            float sp0 = sDS[gi*24 + p*8 + (gj>>1)];
            if (gidx < NN) {
                float4 vi = make_float4(0,0,0,0);
                if (l > 0) vi = *(const float4*)(vin + (size_t)p*N64 + (size_t)gidx*64 + gj*4);
                float4 o;
                o.x = (vi.x + t0.x + wd4.x*sp0)*g0v.x;
                o.y = (vi.y + t0.y + wd4.y*sp0)*g0v.y;
                o.z = (vi.z + t0.z + wd4.z*sp0)*g0v.z;
                o.w = (vi.w + t0.w + wd4.w*sp0)*g0v.w;
                *(float4*)(vout + (size_t)p*N64 + (size_t)gidx*64 + gj*4) = o;
            }
        }
    }
    __syncthreads();   // done reading sW(Wc), sVA, sDS

    // ---- P5: FFN via MFMA, half-at-a-time through sM ----
    stagePK(W1_l, 128); __syncthreads();            // W1 cols 0..63
    {
        f32x4 u = {0.f,0.f,0.f,0.f};
        mfma_gemm(sHh, sHl, u);
        #pragma unroll
        for (int r = 0; r < 4; ++r) u[r] = gelu_f(u[r]);
        storeMid(u);
    }
    __syncthreads();                                 // done sW(W1h0); sM mid ready
    stagePK(W2_l, 64); __syncthreads();              // W2 rows 0..63
    f32x4 accS = {0.f,0.f,0.f,0.f};
    mfma_gemm(sMh, sMl, accS);
    __syncthreads();                                 // done sW(W2a), sM
    stagePK(W1_l + 64, 128); __syncthreads();        // W1 cols 64..127
    {
        f32x4 u = {0.f,0.f,0.f,0.f};
        mfma_gemm(sHh, sHl, u);
        #pragma unroll
        for (int r = 0; r < 4; ++r) u[r] = gelu_f(u[r]);
        storeMid(u);
    }
    __syncthreads();                                 // done sW(W1h1); sM mid2 ready
    stagePK(W2_l + 64*64, 64); __syncthreads();      // W2 rows 64..127
    mfma_gemm(sMh, sMl, accS);
    addToS(accS);
    __syncthreads();                                 // sS stable; done sW(W2b), sM

    // ---- P6: next-layer q/k/vf (MFMA) or pooling ----
    if (l < LAYERS-1) {
        ln_split();
        stagePK(Wk + (l+1)*4096, 64);
        __syncthreads();
        { f32x4 c = {0.f,0.f,0.f,0.f}; mfma_gemm(sHh, sHl, c); storeG2(kout, c); }
        __syncthreads();
        stagePK(Wv + (l+1)*4096, 64); __syncthreads();
        { f32x4 c = {0.f,0.f,0.f,0.f}; mfma_gemm(sHh, sHl, c); storeG2(vfout, c); }
        __syncthreads();
        stagePK(Wq + (l+1)*4096, 64); __syncthreads();
        { f32x4 c = {0.f,0.f,0.f,0.f}; mfma_gemm(sHh, sHl, c); storeG2(qout, c); }
        {
            int ga = a0 + gi;
            if (ga < NN)
                ((float4*)(sg + (size_t)ga*64))[gj] = ((float4*)(sS + gi*LDA))[gj];
        }
    } else {
        int ga = a0 + gi;
        if (ga < NN) {
            int r = ridx[n2o[ga]];
            #pragma unroll
            for (int e = 0; e < 4; ++e)
                atomicAdd(&resb[r*64 + gj*4 + e], sS[gi*LDA + gj*4 + e]);
        }
    }
}

// ---------------- head ----------------
__global__ void head_kernel(const float* __restrict__ res, const float* __restrict__ Wout,
                            const float* __restrict__ bout, float* __restrict__ out, int r_total) {
    int wave = threadIdx.x >> 6, lane = threadIdx.x & 63;
    int r = blockIdx.x*4 + wave;
    if (r >= r_total) return;
    float p = res[r*HID + lane] * (1.0f/APR);
    float o0 = p * Wout[lane*2 + 0];
    float o1 = p * Wout[lane*2 + 1];
    #pragma unroll
    for (int off = 1; off < 64; off <<= 1) { o0 += __shfl_xor(o0, off); o1 += __shfl_xor(o1, off); }
    if (lane == 0) { out[r*2+0] = o0 + bout[0]; out[r*2+1] = o1 + bout[1]; }
}

// ---------------- launcher ----------------
extern "C" void kernel_launch(void* const* d_in, const int* in_sizes, int n_in,
                              void* d_out, int out_size, void* d_ws, size_t ws_size,
                              hipStream_t stream) {
    const float* coords    = (const float*)d_in[0];
    const int*   atom_ids  = (const int*)d_in[1];
    const int*   res_ids   = (const int*)d_in[2];
    const int*   elem_ids  = (const int*)d_in[3];
    const int*   ridx      = (const int*)d_in[4];
    const float* emb_atom  = (const float*)d_in[5];
    const float* emb_res   = (const float*)d_in[6];
    const float* emb_elem  = (const float*)d_in[7];
    const float* Win       = (const float*)d_in[8];
    const float* Wq        = (const float*)d_in[9];
    const float* Wk        = (const float*)d_in[10];
    const float* Wv        = (const float*)d_in[11];
    const float* Wvec      = (const float*)d_in[12];
    const float* wdir      = (const float*)d_in[13];
    const float* dist_bias = (const float*)d_in[14];
    const float* Wo        = (const float*)d_in[15];
    const float* W1        = (const float*)d_in[16];
    const float* W2        = (const float*)d_in[17];
    const float* Wg        = (const float*)d_in[18];
    const float* Wout      = (const float*)d_in[19];
    const float* bout      = (const float*)d_in[20];
    float* out = (float*)d_out;

    float* ws = (float*)d_ws;
    float* qA = ws + OFF_QA;  float* kA = ws + OFF_KA;  float* fA = ws + OFF_FA;
    float* qB = ws + OFF_QB;  float* kB = ws + OFF_KB;  float* fB = ws + OFF_FB;
    float* vA = ws + OFF_VA;  float* vB = ws + OFF_VB;
    float* sg = ws + OFF_S;
    float* dirn_s = ws + OFF_DIRNS;
    float4* c4  = (float4*)(ws + OFF_C4);
    float4* c4s = (float4*)(ws + OFF_C4S);
    float* resb = ws + OFF_RES;
    int* nbr_s  = (int*)(ws + OFF_NBRS);
    int* bins_s = (int*)(ws + OFF_BINSS);
    int* o2n    = (int*)(ws + OFF_O2N);
    int* n2o    = (int*)(ws + OFF_N2O);
    int* cellid = (int*)(ws + OFF_CELL);
    int* hist   = (int*)(ws + OFF_HIST);
    int* cnt    = (int*)(ws + OFF_CNT);
    int* baseb  = (int*)(ws + OFF_BASE);

    hipMemsetAsync(hist, 0, 2*4096*sizeof(int), stream);

    pad_cell_kernel<<<(NN+255)/256, 256, 0, stream>>>(coords, c4, cellid, hist, resb, NN);
    scan_kernel<<<1, 256, 0, stream>>>(hist, baseb);
    scatter_kernel<<<(NN+255)/256, 256, 0, stream>>>(cellid, baseb, cnt, o2n, n2o, c4, c4s, NN);
    knn_grid_kernel<<<(NN+3)/4, 256, 0, stream>>>(c4s, baseb, hist, n2o, o2n, nbr_s, bins_s, dirn_s, NN);

    prologue_kernel<<<NBLK, 256, 0, stream>>>(atom_ids, res_ids, elem_ids, n2o,
                                              emb_atom, emb_res, emb_elem,
                                              Win, Wq, Wk, Wv, sg, qA, kA, fA);
    for (int l = 0; l < LAYERS; ++l) {
        int p = l & 1;
        const float* qin = p ? qB : qA;  float* qout = p ? qA : qB;
        const float* kin = p ? kB : kA;  float* kout = p ? kA : kB;
        const float* fin = p ? fB : fA;  float* fout = p ? fA : fB;
        const float* vin = p ? vB : vA;  float* vout = p ? vA : vB;
        layer_kernel<<<NBLK, 512, 0, stream>>>(qin, kin, fin, qout, kout, fout,
                                               vin, vout, sg, dirn_s, nbr_s, bins_s,
                                               resb, ridx, n2o,
                                               Wvec, wdir, dist_bias,
                                               Wo, W1, W2, Wg, Wq, Wk, Wv, l);
    }
    head_kernel<<<(RR+3)/4, 256, 0, stream>>>(resb, Wout, bout, out, RR);
}

// Round 5
// 584.257 us; speedup vs baseline: 1.4939x; 1.4939x over previous
//
#include <hip/hip_runtime.h>
#include <cfloat>

// ---- problem dims ----
#define NN    16380
#define RR    819
#define APR   20
#define KNB   16
#define HID   64
#define LAYERS 6
#define BINS  100
#define N64   (NN*HID)

// ---- geometry ----
#define ATB   32
#define NBLK  512               // 512*32 = 16384 >= NN
#define LDA   68
#define LDU   132
#define CSIZE 4.375f            // 70/16

// ---- workspace float offsets ----
#define OFF_QA    0
#define OFF_KA    (1*N64)
#define OFF_FA    (2*N64)
#define OFF_QB    (3*N64)
#define OFF_KB    (4*N64)
#define OFF_FB    (5*N64)
#define OFF_VA    (6*N64)           // 3 planes
#define OFF_VB    (9*N64)           // 3 planes
#define OFF_S     (12*N64)
#define OFF_DIRNS (13*N64)          // N*48 (sorted space)
#define OFF_C4    (OFF_DIRNS + NN*48)
#define OFF_C4S   (OFF_C4 + NN*4)
#define OFF_RES   (OFF_C4S + NN*4)
#define OFF_NBRS  (OFF_RES + RR*64)    // int N*16 (sorted space)
#define OFF_BINSS (OFF_NBRS + NN*16)   // int N*16
#define OFF_O2N   (OFF_BINSS + NN*16)  // int N
#define OFF_N2O   (OFF_O2N + NN)       // int N
#define OFF_CELL  (OFF_N2O + NN)       // int N
#define OFF_HIST  (OFF_CELL + NN)      // int 4096
#define OFF_CNT   (OFF_HIST + 4096)    // int 4096 (adjacent: one memset covers both)
#define OFF_BASE  (OFF_CNT + 4096)     // int 4096

typedef unsigned long long u64;
#define U64MAX 0xFFFFFFFFFFFFFFFFull

__device__ __forceinline__ float gelu_f(float x) {
    float x3 = x*x*x;
    float t = tanhf(0.7978845608028654f*(x + 0.044715f*x3));
    return 0.5f*x*(1.0f+t);
}
__device__ __forceinline__ float sigmoid_f(float x) {
    return 1.0f/(1.0f + expf(-x));
}
__device__ __forceinline__ int spread3(int x) {   // 4-bit -> every 3rd bit
    return (x&1) | ((x&2)<<2) | ((x&4)<<4) | ((x&8)<<6);
}
__device__ __forceinline__ unsigned sortable_u32(float f) {
    unsigned u = __float_as_uint(f);
    return u ^ ((u & 0x80000000u) ? 0xFFFFFFFFu : 0x80000000u);
}

// ---------------- fused pad + cell-id + histogram + resb zero ----------------
__global__ void pad_cell_kernel(const float* __restrict__ coords, float4* __restrict__ c4,
                                int* __restrict__ cellid, int* __restrict__ hist,
                                float* __restrict__ resb, int n) {
    int i = blockIdx.x*256 + threadIdx.x;
    for (int j = i; j < RR*HID; j += 16384) resb[j] = 0.f;
    if (i >= n) return;
    float x = coords[3*i], y = coords[3*i+1], z = coords[3*i+2];
    float sq = __fadd_rn(__fadd_rn(__fmul_rn(x,x), __fmul_rn(y,y)), __fmul_rn(z,z));
    c4[i] = make_float4(x, y, z, sq);
    int cx = min(15, max(0, (int)(x * (16.0f/70.0f))));
    int cy = min(15, max(0, (int)(y * (16.0f/70.0f))));
    int cz = min(15, max(0, (int)(z * (16.0f/70.0f))));
    int m = spread3(cx) | (spread3(cy)<<1) | (spread3(cz)<<2);
    cellid[i] = m;
    atomicAdd(&hist[m], 1);
}
__global__ void scan_kernel(const int* __restrict__ hist, int* __restrict__ base) {
    __shared__ int part[256];
    int t = threadIdx.x;
    int loc[16]; int s = 0;
    #pragma unroll
    for (int e = 0; e < 16; ++e) { loc[e] = s; s += hist[t*16+e]; }
    part[t] = s;
    __syncthreads();
    if (t == 0) { int acc = 0; for (int i = 0; i < 256; ++i) { int v = part[i]; part[i] = acc; acc += v; } }
    __syncthreads();
    int off = part[t];
    #pragma unroll
    for (int e = 0; e < 16; ++e) base[t*16+e] = off + loc[e];
}
__global__ void scatter_kernel(const int* __restrict__ cellid, const int* __restrict__ base,
                               int* __restrict__ cnt, int* __restrict__ o2n,
                               int* __restrict__ n2o, const float4* __restrict__ c4,
                               float4* __restrict__ c4s, int n) {
    int i = blockIdx.x*256 + threadIdx.x;
    if (i >= n) return;
    int m = cellid[i];
    int pos = base[m] + atomicAdd(&cnt[m], 1);
    o2n[i] = pos; n2o[pos] = i;
    c4s[pos] = c4[i];
}

// ---------------- grid kNN: bitonic sort+merge selection (round-5) ----------------
// Round-5: the serial ballot-insertion loop (~64 sequential shfl-chains for the
// first batch, ~10 ops each) was the knn bottleneck (86us, VALUBusy 39%, FETCH
// 1.7MB -> pure serialization). Replaced with: per-64 chunk, full in-register
// bitonic sort across lanes (~21 CE stages), then 5-stage bitonic merge of the
// old top-16 (lanes 0-15, asc) with the chunk top-16 (reversed into lanes 16-31).
// Exact: top16(union) is contained in top16(A) U top16(B); keys embed the
// original atom index -> deterministic order matching top_k tie-break.
#define SCRATCH 1024
__global__ __launch_bounds__(256) void knn_grid_kernel(
    const float4* __restrict__ c4s, const int* __restrict__ base, const int* __restrict__ hist,
    const int* __restrict__ n2o, const int* __restrict__ o2n,
    int* __restrict__ nbr, int* __restrict__ binsO, float* __restrict__ dirn, int n)
{
    __shared__ int sIdx[4][SCRATCH];
    int tid = threadIdx.x;
    int wv = tid >> 6, lane = tid & 63;
    int i = blockIdx.x*4 + wv;
    bool valid = i < n;
    int ii = valid ? i : 0;
    float4 cd = c4s[ii];
    float sqd = cd.w;
    int cx = min(15, max(0, (int)(cd.x * (16.0f/70.0f))));
    int cy = min(15, max(0, (int)(cd.y * (16.0f/70.0f))));
    int cz = min(15, max(0, (int)(cd.z * (16.0f/70.0f))));
    u64 dlist = U64MAX;
    u64 vmax  = U64MAX;
    int* sidx = sIdx[wv];

    auto compute_pk = [&](int idx) -> u64 {
        if (idx == i) return U64MAX;
        float4 cc = c4s[idx];
        float dt = __fmul_rn(cd.x, cc.x);
        dt = __fmaf_rn(cd.y, cc.y, dt);
        dt = __fmaf_rn(cd.z, cc.z, dt);
        float key = __fsub_rn(__fadd_rn(sqd, cc.w), __fmul_rn(2.0f, dt));
        int org = n2o[idx];
        return ((u64)sortable_u32(key) << 32) | (unsigned)org;
    };

    auto process_batch = [&](int M) {
        if (M <= 0) return;
        for (int c0 = 0; c0 < M; c0 += 64) {
            int p = c0 + lane;
            u64 v = (p < M) ? compute_pk(sidx[p]) : U64MAX;
            // ---- bitonic sort: 64 keys ascending across lanes ----
            #pragma unroll
            for (int k = 2; k <= 64; k <<= 1) {
                #pragma unroll
                for (int j = k >> 1; j > 0; j >>= 1) {
                    u64 o = __shfl_xor(v, j);
                    bool keepmin = (((lane & j) == 0) == ((lane & k) == 0));
                    u64 mn = (v < o) ? v : o;
                    u64 mx = (v < o) ? o : v;
                    v = keepmin ? mn : mx;
                }
            }
            // nothing in this chunk can beat the current 16th? (wave-uniform)
            if (__shfl(v, 0) >= vmax) continue;
            // ---- merge: [dlist asc lanes0-15 | chunk top16 desc lanes16-31] ----
            u64 bm = __shfl(v, (31 - lane) & 63);   // lane16->v[15] ... lane31->v[0]
            u64 m = (lane < 16) ? dlist : bm;
            #pragma unroll
            for (int j = 16; j > 0; j >>= 1) {
                u64 o = __shfl_xor(m, j);
                u64 mn = (m < o) ? m : o;
                u64 mx = (m < o) ? o : m;
                m = ((lane & j) == 0) ? mn : mx;
            }
            if (lane < 16) dlist = m;
            vmax = __shfl(dlist, 15);
        }
    };

    for (int R = 1; R <= 16; ++R) {
        int side = 2*R+1;
        int ncell = side*side*side;
        int M = 0;
        for (int t0 = 0; t0 < ncell; t0 += 64) {
            int t = t0 + lane;
            int cnt = 0, b = 0;
            if (t < ncell) {
                int dxc = t % side - R;
                int dyc = (t/side) % side - R;
                int dzc = t/(side*side) - R;
                int ch = max(abs(dxc), max(abs(dyc), abs(dzc)));
                bool use = (R == 1) || (ch == R);
                int x = cx+dxc, y = cy+dyc, z = cz+dzc;
                if (use && x>=0 && x<16 && y>=0 && y<16 && z>=0 && z<16) {
                    int m = spread3(x) | (spread3(y)<<1) | (spread3(z)<<2);
                    cnt = hist[m]; b = base[m];
                }
            }
            int incl = cnt;
            #pragma unroll
            for (int o = 1; o < 64; o <<= 1) { int v = __shfl_up(incl, o); if (lane >= o) incl += v; }
            int excl = incl - cnt;
            int tot = __shfl(incl, 63);
            if (M + tot > SCRATCH) { process_batch(M); M = 0; }
            for (int e = 0; e < cnt; ++e) {
                int pos = M + excl + e;
                if (pos < SCRATCH) sidx[pos] = b + e;
            }
            M = min(M + tot, SCRATCH);
        }
        process_batch(M);
        float rim = (float)R * CSIZE;
        unsigned thS = sortable_u32(rim*rim - 0.05f);
        if ((unsigned)(vmax >> 32) < thS) break;
    }
    if (valid && lane < 16) {
        int org = (int)(dlist & 0xFFFFFFFFull);
        int src = o2n[org];
        float4 cs = c4s[src];
        float dx = __fsub_rn(cd.x, cs.x);
        float dy = __fsub_rn(cd.y, cs.y);
        float dz = __fsub_rn(cd.z, cs.z);
        float ss = __fadd_rn(__fadd_rn(__fmul_rn(dx,dx), __fmul_rn(dy,dy)),
                             __fmul_rn(dz,dz));
        float dd = __fsqrt_rn(__fadd_rn(ss, 1e-12f));
        nbr[i*KNB + lane] = src;
        float bf = __fmul_rn(__fdiv_rn(dd, 10.0f), 100.0f);
        int b = (int)bf;
        b = min(max(b, 0), BINS-1);
        binsO[i*KNB + lane] = b;
        dirn[i*48 + lane*3 + 0] = __fdiv_rn(dx, dd);
        dirn[i*48 + lane*3 + 1] = __fdiv_rn(dy, dd);
        dirn[i*48 + lane*3 + 2] = __fdiv_rn(dz, dd);
    }
}

// ---------------- prologue: round-0 verbatim (256 threads, 2 rows/thread) ----------------
__global__ __launch_bounds__(256) void prologue_kernel(
    const int* __restrict__ aid, const int* __restrict__ rid, const int* __restrict__ eid,
    const int* __restrict__ n2o,
    const float* __restrict__ ea, const float* __restrict__ er, const float* __restrict__ ee,
    const float* __restrict__ Win, const float* __restrict__ Wq, const float* __restrict__ Wk,
    const float* __restrict__ Wv,
    float* __restrict__ sg, float* __restrict__ qout, float* __restrict__ kout,
    float* __restrict__ vfout)
{
    __shared__ __align__(16) float sS[ATB*LDA];
    __shared__ __align__(16) float sH[ATB*LDA];
    __shared__ __align__(16) float sW[4096];
    const int tid = threadIdx.x;
    const int a0 = blockIdx.x*ATB;
    const int gi = tid>>4, gj = tid&15;
    const int lrow = tid>>3, lsub = tid&7;

    auto stageW = [&](const float* W) {
        const float4* src = (const float4*)W; float4* dst = (float4*)sW;
        #pragma unroll
        for (int r = 0; r < 4; ++r) dst[tid + 256*r] = src[tid + 256*r];
    };
    auto do_gemm = [&](const float* sA, float4& c0, float4& c1) {
        const float* a0p = sA + gi*LDA;
        const float* a1p = sA + (gi+16)*LDA;
        const float* wr  = sW + gj*4;
        #pragma unroll 8
        for (int k = 0; k < 64; ++k) {
            float av0 = a0p[k], av1 = a1p[k];
            float4 w = *(const float4*)(wr + k*64);
            c0.x = fmaf(av0,w.x,c0.x); c0.y = fmaf(av0,w.y,c0.y);
            c0.z = fmaf(av0,w.z,c0.z); c0.w = fmaf(av0,w.w,c0.w);
            c1.x = fmaf(av1,w.x,c1.x); c1.y = fmaf(av1,w.y,c1.y);
            c1.z = fmaf(av1,w.z,c1.z); c1.w = fmaf(av1,w.w,c1.w);
        }
    };
    auto do_ln = [&](const float* src, float* dst) {
        const float* sp = src + lrow*LDA + lsub*8;
        float v[8]; float s1 = 0.f;
        #pragma unroll
        for (int e = 0; e < 8; ++e) { v[e] = sp[e]; s1 += v[e]; }
        s1 += __shfl_xor(s1,1); s1 += __shfl_xor(s1,2); s1 += __shfl_xor(s1,4);
        float mean = s1*(1.0f/64.0f);
        float s2 = 0.f;
        #pragma unroll
        for (int e = 0; e < 8; ++e) { float t = v[e]-mean; s2 += t*t; }
        s2 += __shfl_xor(s2,1); s2 += __shfl_xor(s2,2); s2 += __shfl_xor(s2,4);
        float sc = 1.0f/sqrtf(s2*(1.0f/64.0f)+1e-5f);
        float* dp = dst + lrow*LDA + lsub*8;
        #pragma unroll
        for (int e = 0; e < 8; ++e) dp[e] = (v[e]-mean)*sc;
    };
    auto store_g = [&](float* base, float4 c0, float4 c1) {
        int g0 = a0+gi, g1 = a0+gi+16;
        if (g0 < NN) *(float4*)(base + (size_t)g0*64 + gj*4) = c0;
        if (g1 < NN) *(float4*)(base + (size_t)g1*64 + gj*4) = c1;
    };

    {   // feat -> sH  (overlapped with Win staging; both guarded by next sync)
        int ga = a0 + lrow;
        int io = (ga < NN) ? n2o[ga] : 0;
        #pragma unroll
        for (int e = 0; e < 8; ++e) {
            int c = lsub*8 + e;
            float x = 0.f;
            if (ga < NN) {
                if (c < 32)      x = ea[aid[io]*32 + c];
                else if (c < 48) x = er[rid[io]*16 + (c-32)];
                else             x = ee[eid[io]*16 + (c-48)];
            }
            sH[lrow*LDA + c] = x;
        }
    }
    stageW(Win);
    __syncthreads();
    {
        float4 c0 = make_float4(0,0,0,0), c1 = c0;
        do_gemm(sH, c0, c1);
        *(float4*)(sS + gi*LDA + gj*4)      = c0;
        *(float4*)(sS + (gi+16)*LDA + gj*4) = c1;
        store_g(sg, c0, c1);
    }
    __syncthreads();                 // all done with sH(feat), sW(Win); sS written
    do_ln(sS, sH);                   // overlap LN with Wk staging
    stageW(Wk);
    __syncthreads();
    { float4 c0 = make_float4(0,0,0,0), c1 = c0; do_gemm(sH, c0, c1); store_g(kout, c0, c1); }
    __syncthreads();
    stageW(Wv); __syncthreads();
    { float4 c0 = make_float4(0,0,0,0), c1 = c0; do_gemm(sH, c0, c1); store_g(vfout, c0, c1); }
    __syncthreads();
    stageW(Wq); __syncthreads();
    { float4 c0 = make_float4(0,0,0,0), c1 = c0; do_gemm(sH, c0, c1); store_g(qout, c0, c1); }
}

// ---------------- fused layer kernel: round-0 verbatim (best measured, 89.5us) ----------------
__global__ __launch_bounds__(256) void layer_kernel(
    const float* __restrict__ qin, const float* __restrict__ kin, const float* __restrict__ vfin,
    float* __restrict__ qout, float* __restrict__ kout, float* __restrict__ vfout,
    const float* __restrict__ vin, float* __restrict__ vout,
    float* __restrict__ sg, const float* __restrict__ dirn,
    const int* __restrict__ nbr, const int* __restrict__ bins,
    float* __restrict__ resb, const int* __restrict__ ridx, const int* __restrict__ n2o,
    const float* __restrict__ Wvec, const float* __restrict__ wdir,
    const float* __restrict__ dist_bias,
    const float* __restrict__ Wo, const float* __restrict__ W1, const float* __restrict__ W2,
    const float* __restrict__ Wg, const float* __restrict__ Wq, const float* __restrict__ Wk,
    const float* __restrict__ Wv, int l)
{
    __shared__ __align__(16) float sS[ATB*LDA];
    __shared__ __align__(16) float sH[ATB*LDA];
    __shared__ __align__(16) float sM[ATB*LDU];
    __shared__ __align__(16) float sVA[3][ATB*LDA];
    __shared__ __align__(16) float sW[4096];
    __shared__ float sDS[ATB*24];

    const int tid = threadIdx.x;
    const int bswz = (blockIdx.x & 7) * (NBLK/8) + (blockIdx.x >> 3);
    const int a0 = bswz*ATB;
    const int gi = tid>>4, gj = tid&15;
    const int lrow = tid>>3, lsub = tid&7;
    const int wv = tid>>6, lane = tid&63;

    const float* Wo_l = Wo + l*4096;
    const float* Wg_l = Wg + l*4096;
    const float* Wc_l = Wvec + l*4096;
    const float* W1_l = W1 + l*8192;
    const float* W2_l = W2 + l*8192;
    const float* db_l = dist_bias + l*BINS*8;
    const float* wd_l = wdir + l*64;

    auto stageW = [&](const float* W) {
        const float4* src = (const float4*)W; float4* dst = (float4*)sW;
        #pragma unroll
        for (int r = 0; r < 4; ++r) dst[tid + 256*r] = src[tid + 256*r];
    };
    auto stageW1h = [&](const float* W1l, int h) {
        const float4* src = (const float4*)W1l; float4* dst = (float4*)sW;
        #pragma unroll
        for (int r = 0; r < 4; ++r) {
            int q = tid + 256*r;
            int row = q >> 4, c4i = q & 15;
            dst[q] = src[row*32 + h*16 + c4i];
        }
    };
    auto do_gemm = [&](const float* sA, int lda, int ko, float4& c0, float4& c1) {
        const float* a0p = sA + gi*lda + ko;
        const float* a1p = sA + (gi+16)*lda + ko;
        const float* wr  = sW + gj*4;
        #pragma unroll 8
        for (int k = 0; k < 64; ++k) {
            float av0 = a0p[k], av1 = a1p[k];
            float4 w = *(const float4*)(wr + k*64);
            c0.x = fmaf(av0,w.x,c0.x); c0.y = fmaf(av0,w.y,c0.y);
            c0.z = fmaf(av0,w.z,c0.z); c0.w = fmaf(av0,w.w,c0.w);
            c1.x = fmaf(av1,w.x,c1.x); c1.y = fmaf(av1,w.y,c1.y);
            c1.z = fmaf(av1,w.z,c1.z); c1.w = fmaf(av1,w.w,c1.w);
        }
    };
    auto do_ln = [&](const float* src, float* dst) {
        const float* sp = src + lrow*LDA + lsub*8;
        float v[8]; float s1 = 0.f;
        #pragma unroll
        for (int e = 0; e < 8; ++e) { v[e] = sp[e]; s1 += v[e]; }
        s1 += __shfl_xor(s1,1); s1 += __shfl_xor(s1,2); s1 += __shfl_xor(s1,4);
        float mean = s1*(1.0f/64.0f);
        float s2 = 0.f;
        #pragma unroll
        for (int e = 0; e < 8; ++e) { float t = v[e]-mean; s2 += t*t; }
        s2 += __shfl_xor(s2,1); s2 += __shfl_xor(s2,2); s2 += __shfl_xor(s2,4);
        float sc = 1.0f/sqrtf(s2*(1.0f/64.0f)+1e-5f);
        float* dp = dst + lrow*LDA + lsub*8;
        #pragma unroll
        for (int e = 0; e < 8; ++e) dp[e] = (v[e]-mean)*sc;
    };
    auto store_g = [&](float* base, float4 c0, float4 c1) {
        int g0 = a0+gi, g1 = a0+gi+16;
        if (g0 < NN) *(float4*)(base + (size_t)g0*64 + gj*4) = c0;
        if (g1 < NN) *(float4*)(base + (size_t)g1*64 + gj*4) = c1;
    };

    // ---- P0: load s ----
    {
        int ga = a0 + lrow;
        float4 z = make_float4(0,0,0,0);
        float4 x0 = z, x1 = z;
        if (ga < NN) {
            const float4* sp = (const float4*)(sg + (size_t)ga*64);
            x0 = sp[lsub*2]; x1 = sp[lsub*2+1];
        }
        float4* dp = (float4*)(sS + lrow*LDA);
        dp[lsub*2] = x0; dp[lsub*2+1] = x1;
    }
    // prestage Wo: sW is idle during attention; guarded by the post-attention sync
    stageW(Wo_l);

    // ---- P1: attention ----
    for (int aa = 0; aa < 8; ++aa) {
        int la = wv*8 + aa;
        int ga = a0 + la;
        if (ga >= NN) break;
        float qh = qin[(size_t)ga*64 + lane];
        float lg[KNB]; int nb[KNB];
        #pragma unroll
        for (int k = 0; k < KNB; ++k) {
            int j = nbr[ga*KNB + k];
            nb[k] = j;
            float t = qh * kin[(size_t)j*64 + lane];
            t += __shfl_xor(t,1); t += __shfl_xor(t,2); t += __shfl_xor(t,4);
            lg[k] = t*0.35355339059327373f + db_l[bins[ga*KNB+k]*8 + (lane>>3)];
        }
        float m = lg[0];
        #pragma unroll
        for (int k = 1; k < KNB; ++k) m = fmaxf(m, lg[k]);
        float ssum = 0.f;
        #pragma unroll
        for (int k = 0; k < KNB; ++k) { lg[k] = expf(lg[k]-m); ssum += lg[k]; }
        float inv = 1.0f/ssum;
        float mh=0.f, b0=0.f, b1=0.f, b2=0.f, s0=0.f, s1=0.f, s2=0.f;
        if (l > 0) {
            #pragma unroll
            for (int k = 0; k < KNB; ++k) {
                float w = lg[k]*inv; int j = nb[k];
                mh += w * vfin[(size_t)j*64 + lane];
                b0 += w * vin[(size_t)j*64 + lane];
                b1 += w * vin[(size_t)N64 + (size_t)j*64 + lane];
                b2 += w * vin[2*(size_t)N64 + (size_t)j*64 + lane];
                s0 += w * dirn[ga*48 + k*3 + 0];
                s1 += w * dirn[ga*48 + k*3 + 1];
                s2 += w * dirn[ga*48 + k*3 + 2];
            }
            sVA[0][la*LDA + lane] = b0;
            sVA[1][la*LDA + lane] = b1;
            sVA[2][la*LDA + lane] = b2;
        } else {
            #pragma unroll
            for (int k = 0; k < KNB; ++k) {
                float w = lg[k]*inv; int j = nb[k];
                mh += w * vfin[(size_t)j*64 + lane];
                s0 += w * dirn[ga*48 + k*3 + 0];
                s1 += w * dirn[ga*48 + k*3 + 1];
                s2 += w * dirn[ga*48 + k*3 + 2];
            }
        }
        sM[la*LDU + lane] = mh;
        if ((lane & 7) == 0) {
            int hh = lane >> 3;
            sDS[la*24 + 0*8 + hh] = s0;
            sDS[la*24 + 1*8 + hh] = s1;
            sDS[la*24 + 2*8 + hh] = s2;
        }
    }
    __syncthreads();   // covers: P0 sS, attention sM/sVA/sDS, Wo staging

    // ---- P2: s += msg @ Wo (own-cell read/write; no intra-phase hazard) ----
    {
        float4 c0 = *(float4*)(sS + gi*LDA + gj*4);
        float4 c1 = *(float4*)(sS + (gi+16)*LDA + gj*4);
        do_gemm(sM, LDU, 0, c0, c1);
        *(float4*)(sS + gi*LDA + gj*4)      = c0;
        *(float4*)(sS + (gi+16)*LDA + gj*4) = c1;
    }
    __syncthreads();   // sS stable; all done reading sW(Wo)

    // ---- P3: h2 = LN(s) (overlap Wg staging) ----
    do_ln(sS, sH);
    stageW(Wg_l);
    __syncthreads();

    // ---- P4: gate + vector update ----
    {
        float4 g0 = make_float4(0,0,0,0), g1 = g0;
        do_gemm(sH, LDA, 0, g0, g1);
        g0.x=sigmoid_f(g0.x); g0.y=sigmoid_f(g0.y); g0.z=sigmoid_f(g0.z); g0.w=sigmoid_f(g0.w);
        g1.x=sigmoid_f(g1.x); g1.y=sigmoid_f(g1.y); g1.z=sigmoid_f(g1.z); g1.w=sigmoid_f(g1.w);
        __syncthreads();            // all done reading sW(Wg)
        stageW(Wc_l); __syncthreads();
        float4 wd4 = *(const float4*)&wd_l[gj*4];
        int g0i = a0+gi, g1i = a0+gi+16;
        #pragma unroll
        for (int p = 0; p < 3; ++p) {
            float4 t0 = make_float4(0,0,0,0), t1 = t0;
            if (l > 0) do_gemm(sVA[p], LDA, 0, t0, t1);
            float sp0 = sDS[gi*24 + p*8 + (gj>>1)];
            float sp1 = sDS[(gi+16)*24 + p*8 + (gj>>1)];
            if (g0i < NN) {
                float4 vi = make_float4(0,0,0,0);
                if (l > 0) vi = *(const float4*)(vin + (size_t)p*N64 + (size_t)g0i*64 + gj*4);
                float4 o;
                o.x = (vi.x + t0.x + wd4.x*sp0)*g0.x;
                o.y = (vi.y + t0.y + wd4.y*sp0)*g0.y;
                o.z = (vi.z + t0.z + wd4.z*sp0)*g0.z;
                o.w = (vi.w + t0.w + wd4.w*sp0)*g0.w;
                *(float4*)(vout + (size_t)p*N64 + (size_t)g0i*64 + gj*4) = o;
            }
            if (g1i < NN) {
                float4 vi = make_float4(0,0,0,0);
                if (l > 0) vi = *(const float4*)(vin + (size_t)p*N64 + (size_t)g1i*64 + gj*4);
                float4 o;
                o.x = (vi.x + t1.x + wd4.x*sp1)*g1.x;
                o.y = (vi.y + t1.y + wd4.y*sp1)*g1.y;
                o.z = (vi.z + t1.z + wd4.z*sp1)*g1.z;
                o.w = (vi.w + t1.w + wd4.w*sp1)*g1.w;
                *(float4*)(vout + (size_t)p*N64 + (size_t)g1i*64 + gj*4) = o;
            }
        }
    }
    __syncthreads();   // all done reading sW(Wc), sVA, sDS

    // ---- P5: FFN (sM writes overlapped with the next weight staging) ----
    stageW1h(W1_l, 0); __syncthreads();
    float4 u0a, u1a;
    {
        float4 c0 = make_float4(0,0,0,0), c1 = c0;
        do_gemm(sH, LDA, 0, c0, c1);
        c0.x=gelu_f(c0.x); c0.y=gelu_f(c0.y); c0.z=gelu_f(c0.z); c0.w=gelu_f(c0.w);
        c1.x=gelu_f(c1.x); c1.y=gelu_f(c1.y); c1.z=gelu_f(c1.z); c1.w=gelu_f(c1.w);
        u0a = c0; u1a = c1;
    }
    __syncthreads();   // all done reading sW(W1h0)
    *(float4*)(sM + gi*LDU + gj*4)      = u0a;
    *(float4*)(sM + (gi+16)*LDU + gj*4) = u1a;
    stageW1h(W1_l, 1);
    __syncthreads();
    float4 u0b, u1b;
    {
        float4 c0 = make_float4(0,0,0,0), c1 = c0;
        do_gemm(sH, LDA, 0, c0, c1);
        c0.x=gelu_f(c0.x); c0.y=gelu_f(c0.y); c0.z=gelu_f(c0.z); c0.w=gelu_f(c0.w);
        c1.x=gelu_f(c1.x); c1.y=gelu_f(c1.y); c1.z=gelu_f(c1.z); c1.w=gelu_f(c1.w);
        u0b = c0; u1b = c1;
    }
    __syncthreads();   // all done reading sW(W1h1)
    *(float4*)(sM + gi*LDU + 64 + gj*4)      = u0b;
    *(float4*)(sM + (gi+16)*LDU + 64 + gj*4) = u1b;
    stageW(W2_l);
    __syncthreads();
    {
        float4 c0 = *(float4*)(sS + gi*LDA + gj*4);
        float4 c1 = *(float4*)(sS + (gi+16)*LDA + gj*4);
        do_gemm(sM, LDU, 0, c0, c1);
        __syncthreads();            // all done reading sW(W2a)
        stageW(W2_l + 4096); __syncthreads();
        do_gemm(sM, LDU, 64, c0, c1);
        *(float4*)(sS + gi*LDA + gj*4)      = c0;
        *(float4*)(sS + (gi+16)*LDA + gj*4) = c1;
    }
    __syncthreads();   // sS stable; all done reading sW(W2b), sM

    // ---- P6: next-layer q/k/vf or pooling ----
    if (l < LAYERS-1) {
        do_ln(sS, sH);
        stageW(Wk + (l+1)*4096);    // overlap with LN
        __syncthreads();
        { float4 c0 = make_float4(0,0,0,0), c1 = c0; do_gemm(sH, LDA, 0, c0, c1); store_g(kout, c0, c1); }
        __syncthreads();
        stageW(Wv + (l+1)*4096); __syncthreads();
        { float4 c0 = make_float4(0,0,0,0), c1 = c0; do_gemm(sH, LDA, 0, c0, c1); store_g(vfout, c0, c1); }
        __syncthreads();
        stageW(Wq + (l+1)*4096); __syncthreads();
        { float4 c0 = make_float4(0,0,0,0), c1 = c0; do_gemm(sH, LDA, 0, c0, c1); store_g(qout, c0, c1); }
        {
            int ga = a0 + lrow;
            if (ga < NN) {
                float4* dp = (float4*)(sg + (size_t)ga*64);
                const float4* sp = (const float4*)(sS + lrow*LDA);
                dp[lsub*2] = sp[lsub*2]; dp[lsub*2+1] = sp[lsub*2+1];
            }
        }
    } else {
        int ga = a0 + lrow;
        if (ga < NN) {
            int r = ridx[n2o[ga]];
            #pragma unroll
            for (int e = 0; e < 8; ++e)
                atomicAdd(&resb[r*64 + lsub*8 + e], sS[lrow*LDA + lsub*8 + e]);
        }
    }
}

// ---------------- head ----------------
__global__ void head_kernel(const float* __restrict__ res, const float* __restrict__ Wout,
                            const float* __restrict__ bout, float* __restrict__ out, int r_total) {
    int wave = threadIdx.x >> 6, lane = threadIdx.x & 63;
    int r = blockIdx.x*4 + wave;
    if (r >= r_total) return;
    float p = res[r*HID + lane] * (1.0f/APR);
    float o0 = p * Wout[lane*2 + 0];
    float o1 = p * Wout[lane*2 + 1];
    #pragma unroll
    for (int off = 1; off < 64; off <<= 1) { o0 += __shfl_xor(o0, off); o1 += __shfl_xor(o1, off); }
    if (lane == 0) { out[r*2+0] = o0 + bout[0]; out[r*2+1] = o1 + bout[1]; }
}

// ---------------- launcher ----------------
extern "C" void kernel_launch(void* const* d_in, const int* in_sizes, int n_in,
                              void* d_out, int out_size, void* d_ws, size_t ws_size,
                              hipStream_t stream) {
    const float* coords    = (const float*)d_in[0];
    const int*   atom_ids  = (const int*)d_in[1];
    const int*   res_ids   = (const int*)d_in[2];
    const int*   elem_ids  = (const int*)d_in[3];
    const int*   ridx      = (const int*)d_in[4];
    const float* emb_atom  = (const float*)d_in[5];
    const float* emb_res   = (const float*)d_in[6];
    const float* emb_elem  = (const float*)d_in[7];
    const float* Win       = (const float*)d_in[8];
    const float* Wq        = (const float*)d_in[9];
    const float* Wk        = (const float*)d_in[10];
    const float* Wv        = (const float*)d_in[11];
    const float* Wvec      = (const float*)d_in[12];
    const float* wdir      = (const float*)d_in[13];
    const float* dist_bias = (const float*)d_in[14];
    const float* Wo        = (const float*)d_in[15];
    const float* W1        = (const float*)d_in[16];
    const float* W2        = (const float*)d_in[17];
    const float* Wg        = (const float*)d_in[18];
    const float* Wout      = (const float*)d_in[19];
    const float* bout      = (const float*)d_in[20];
    float* out = (float*)d_out;

    float* ws = (float*)d_ws;
    float* qA = ws + OFF_QA;  float* kA = ws + OFF_KA;  float* fA = ws + OFF_FA;
    float* qB = ws + OFF_QB;  float* kB = ws + OFF_KB;  float* fB = ws + OFF_FB;
    float* vA = ws + OFF_VA;  float* vB = ws + OFF_VB;
    float* sg = ws + OFF_S;
    float* dirn_s = ws + OFF_DIRNS;
    float4* c4  = (float4*)(ws + OFF_C4);
    float4* c4s = (float4*)(ws + OFF_C4S);
    float* resb = ws + OFF_RES;
    int* nbr_s  = (int*)(ws + OFF_NBRS);
    int* bins_s = (int*)(ws + OFF_BINSS);
    int* o2n    = (int*)(ws + OFF_O2N);
    int* n2o    = (int*)(ws + OFF_N2O);
    int* cellid = (int*)(ws + OFF_CELL);
    int* hist   = (int*)(ws + OFF_HIST);
    int* cnt    = (int*)(ws + OFF_CNT);
    int* baseb  = (int*)(ws + OFF_BASE);

    hipMemsetAsync(hist, 0, 2*4096*sizeof(int), stream);

    pad_cell_kernel<<<(NN+255)/256, 256, 0, stream>>>(coords, c4, cellid, hist, resb, NN);
    scan_kernel<<<1, 256, 0, stream>>>(hist, baseb);
    scatter_kernel<<<(NN+255)/256, 256, 0, stream>>>(cellid, baseb, cnt, o2n, n2o, c4, c4s, NN);
    knn_grid_kernel<<<(NN+3)/4, 256, 0, stream>>>(c4s, baseb, hist, n2o, o2n, nbr_s, bins_s, dirn_s, NN);

    prologue_kernel<<<NBLK, 256, 0, stream>>>(atom_ids, res_ids, elem_ids, n2o,
                                              emb_atom, emb_res, emb_elem,
                                              Win, Wq, Wk, Wv, sg, qA, kA, fA);
    for (int l = 0; l < LAYERS; ++l) {
        int p = l & 1;
        const float* qin = p ? qB : qA;  float* qout = p ? qA : qB;
        const float* kin = p ? kB : kA;  float* kout = p ? kA : kB;
        const float* fin = p ? fB : fA;  float* fout = p ? fA : fB;
        const float* vin = p ? vB : vA;  float* vout = p ? vA : vB;
        layer_kernel<<<NBLK, 256, 0, stream>>>(qin, kin, fin, qout, kout, fout,
                                               vin, vout, sg, dirn_s, nbr_s, bins_s,
                                               resb, ridx, n2o,
                                               Wvec, wdir, dist_bias,
                                               Wo, W1, W2, Wg, Wq, Wk, Wv, l);
    }
    head_kernel<<<(RR+3)/4, 256, 0, stream>>>(resb, Wout, bout, out, RR);
}

// Round 6
// 575.697 us; speedup vs baseline: 1.5161x; 1.0149x over previous
//
#include <hip/hip_runtime.h>
#include <cfloat>

// ---- problem dims ----
#define NN    16380
#define RR    819
#define APR   20
#define KNB   16
#define HID   64
#define LAYERS 6
#define BINS  100
#define N64   (NN*HID)

// ---- geometry ----
#define ATB   32
#define NBLK  512               // 512*32 = 16384 >= NN
#define LDA   68
#define LDU   132
#define CSIZE 4.375f            // 70/16

// ---- workspace float offsets ----
#define OFF_QA    0
#define OFF_KA    (1*N64)
#define OFF_FA    (2*N64)
#define OFF_QB    (3*N64)
#define OFF_KB    (4*N64)
#define OFF_FB    (5*N64)
#define OFF_VA    (6*N64)           // 3 planes
#define OFF_VB    (9*N64)           // 3 planes
#define OFF_S     (12*N64)
#define OFF_DIRNS (13*N64)          // N*48 (sorted space)
#define OFF_C4    (OFF_DIRNS + NN*48)
#define OFF_C4S   (OFF_C4 + NN*4)
#define OFF_RES   (OFF_C4S + NN*4)
#define OFF_NBRS  (OFF_RES + RR*64)    // int N*16 (sorted space)
#define OFF_BINSS (OFF_NBRS + NN*16)   // int N*16
#define OFF_O2N   (OFF_BINSS + NN*16)  // int N
#define OFF_N2O   (OFF_O2N + NN)       // int N
#define OFF_CELL  (OFF_N2O + NN)       // int N
#define OFF_HIST  (OFF_CELL + NN)      // int 4096
#define OFF_CNT   (OFF_HIST + 4096)    // int 4096 (adjacent: one memset covers both)
#define OFF_BASE  (OFF_CNT + 4096)     // int 4096

typedef unsigned long long u64;
#define U64MAX 0xFFFFFFFFFFFFFFFFull

__device__ __forceinline__ float gelu_f(float x) {
    float x3 = x*x*x;
    float t = tanhf(0.7978845608028654f*(x + 0.044715f*x3));
    return 0.5f*x*(1.0f+t);
}
__device__ __forceinline__ float sigmoid_f(float x) {
    return 1.0f/(1.0f + expf(-x));
}
__device__ __forceinline__ int spread3(int x) {   // 4-bit -> every 3rd bit
    return (x&1) | ((x&2)<<2) | ((x&4)<<4) | ((x&8)<<6);
}
__device__ __forceinline__ unsigned sortable_u32(float f) {
    unsigned u = __float_as_uint(f);
    return u ^ ((u & 0x80000000u) ? 0xFFFFFFFFu : 0x80000000u);
}

// ---------------- fused pad + cell-id + histogram + resb zero ----------------
__global__ void pad_cell_kernel(const float* __restrict__ coords, float4* __restrict__ c4,
                                int* __restrict__ cellid, int* __restrict__ hist,
                                float* __restrict__ resb, int n) {
    int i = blockIdx.x*256 + threadIdx.x;
    for (int j = i; j < RR*HID; j += 16384) resb[j] = 0.f;
    if (i >= n) return;
    float x = coords[3*i], y = coords[3*i+1], z = coords[3*i+2];
    float sq = __fadd_rn(__fadd_rn(__fmul_rn(x,x), __fmul_rn(y,y)), __fmul_rn(z,z));
    c4[i] = make_float4(x, y, z, sq);
    int cx = min(15, max(0, (int)(x * (16.0f/70.0f))));
    int cy = min(15, max(0, (int)(y * (16.0f/70.0f))));
    int cz = min(15, max(0, (int)(z * (16.0f/70.0f))));
    int m = spread3(cx) | (spread3(cy)<<1) | (spread3(cz)<<2);
    cellid[i] = m;
    atomicAdd(&hist[m], 1);
}
__global__ void scan_kernel(const int* __restrict__ hist, int* __restrict__ base) {
    __shared__ int part[256];
    int t = threadIdx.x;
    int loc[16]; int s = 0;
    #pragma unroll
    for (int e = 0; e < 16; ++e) { loc[e] = s; s += hist[t*16+e]; }
    part[t] = s;
    __syncthreads();
    if (t == 0) { int acc = 0; for (int i = 0; i < 256; ++i) { int v = part[i]; part[i] = acc; acc += v; } }
    __syncthreads();
    int off = part[t];
    #pragma unroll
    for (int e = 0; e < 16; ++e) base[t*16+e] = off + loc[e];
}
__global__ void scatter_kernel(const int* __restrict__ cellid, const int* __restrict__ base,
                               int* __restrict__ cnt, int* __restrict__ o2n,
                               int* __restrict__ n2o, const float4* __restrict__ c4,
                               float4* __restrict__ c4s, int n) {
    int i = blockIdx.x*256 + threadIdx.x;
    if (i >= n) return;
    int m = cellid[i];
    int pos = base[m] + atomicAdd(&cnt[m], 1);
    o2n[i] = pos; n2o[pos] = i;
    c4s[pos] = c4[i];
}

// ---------------- grid kNN: bitonic sort+merge selection (round-5, kept) ----------------
#define SCRATCH 1024
__global__ __launch_bounds__(256) void knn_grid_kernel(
    const float4* __restrict__ c4s, const int* __restrict__ base, const int* __restrict__ hist,
    const int* __restrict__ n2o, const int* __restrict__ o2n,
    int* __restrict__ nbr, int* __restrict__ binsO, float* __restrict__ dirn, int n)
{
    __shared__ int sIdx[4][SCRATCH];
    int tid = threadIdx.x;
    int wv = tid >> 6, lane = tid & 63;
    int i = blockIdx.x*4 + wv;
    bool valid = i < n;
    int ii = valid ? i : 0;
    float4 cd = c4s[ii];
    float sqd = cd.w;
    int cx = min(15, max(0, (int)(cd.x * (16.0f/70.0f))));
    int cy = min(15, max(0, (int)(cd.y * (16.0f/70.0f))));
    int cz = min(15, max(0, (int)(cd.z * (16.0f/70.0f))));
    u64 dlist = U64MAX;
    u64 vmax  = U64MAX;
    int* sidx = sIdx[wv];

    auto compute_pk = [&](int idx) -> u64 {
        if (idx == i) return U64MAX;
        float4 cc = c4s[idx];
        float dt = __fmul_rn(cd.x, cc.x);
        dt = __fmaf_rn(cd.y, cc.y, dt);
        dt = __fmaf_rn(cd.z, cc.z, dt);
        float key = __fsub_rn(__fadd_rn(sqd, cc.w), __fmul_rn(2.0f, dt));
        int org = n2o[idx];
        return ((u64)sortable_u32(key) << 32) | (unsigned)org;
    };

    auto process_batch = [&](int M) {
        if (M <= 0) return;
        for (int c0 = 0; c0 < M; c0 += 64) {
            int p = c0 + lane;
            u64 v = (p < M) ? compute_pk(sidx[p]) : U64MAX;
            // ---- bitonic sort: 64 keys ascending across lanes ----
            #pragma unroll
            for (int k = 2; k <= 64; k <<= 1) {
                #pragma unroll
                for (int j = k >> 1; j > 0; j >>= 1) {
                    u64 o = __shfl_xor(v, j);
                    bool keepmin = (((lane & j) == 0) == ((lane & k) == 0));
                    u64 mn = (v < o) ? v : o;
                    u64 mx = (v < o) ? o : v;
                    v = keepmin ? mn : mx;
                }
            }
            if (__shfl(v, 0) >= vmax) continue;
            // ---- merge: [dlist asc lanes0-15 | chunk top16 desc lanes16-31] ----
            u64 bm = __shfl(v, (31 - lane) & 63);
            u64 m = (lane < 16) ? dlist : bm;
            #pragma unroll
            for (int j = 16; j > 0; j >>= 1) {
                u64 o = __shfl_xor(m, j);
                u64 mn = (m < o) ? m : o;
                u64 mx = (m < o) ? o : m;
                m = ((lane & j) == 0) ? mn : mx;
            }
            if (lane < 16) dlist = m;
            vmax = __shfl(dlist, 15);
        }
    };

    for (int R = 1; R <= 16; ++R) {
        int side = 2*R+1;
        int ncell = side*side*side;
        int M = 0;
        for (int t0 = 0; t0 < ncell; t0 += 64) {
            int t = t0 + lane;
            int cnt = 0, b = 0;
            if (t < ncell) {
                int dxc = t % side - R;
                int dyc = (t/side) % side - R;
                int dzc = t/(side*side) - R;
                int ch = max(abs(dxc), max(abs(dyc), abs(dzc)));
                bool use = (R == 1) || (ch == R);
                int x = cx+dxc, y = cy+dyc, z = cz+dzc;
                if (use && x>=0 && x<16 && y>=0 && y<16 && z>=0 && z<16) {
                    int m = spread3(x) | (spread3(y)<<1) | (spread3(z)<<2);
                    cnt = hist[m]; b = base[m];
                }
            }
            int incl = cnt;
            #pragma unroll
            for (int o = 1; o < 64; o <<= 1) { int v = __shfl_up(incl, o); if (lane >= o) incl += v; }
            int excl = incl - cnt;
            int tot = __shfl(incl, 63);
            if (M + tot > SCRATCH) { process_batch(M); M = 0; }
            for (int e = 0; e < cnt; ++e) {
                int pos = M + excl + e;
                if (pos < SCRATCH) sidx[pos] = b + e;
            }
            M = min(M + tot, SCRATCH);
        }
        process_batch(M);
        float rim = (float)R * CSIZE;
        unsigned thS = sortable_u32(rim*rim - 0.05f);
        if ((unsigned)(vmax >> 32) < thS) break;
    }
    if (valid && lane < 16) {
        int org = (int)(dlist & 0xFFFFFFFFull);
        int src = o2n[org];
        float4 cs = c4s[src];
        float dx = __fsub_rn(cd.x, cs.x);
        float dy = __fsub_rn(cd.y, cs.y);
        float dz = __fsub_rn(cd.z, cs.z);
        float ss = __fadd_rn(__fadd_rn(__fmul_rn(dx,dx), __fmul_rn(dy,dy)),
                             __fmul_rn(dz,dz));
        float dd = __fsqrt_rn(__fadd_rn(ss, 1e-12f));
        nbr[i*KNB + lane] = src;
        float bf = __fmul_rn(__fdiv_rn(dd, 10.0f), 100.0f);
        int b = (int)bf;
        b = min(max(b, 0), BINS-1);
        binsO[i*KNB + lane] = b;
        dirn[i*48 + lane*3 + 0] = __fdiv_rn(dx, dd);
        dirn[i*48 + lane*3 + 1] = __fdiv_rn(dy, dd);
        dirn[i*48 + lane*3 + 2] = __fdiv_rn(dz, dd);
    }
}

// ---------------- prologue: unchanged (256 threads, 2 rows/thread) ----------------
__global__ __launch_bounds__(256) void prologue_kernel(
    const int* __restrict__ aid, const int* __restrict__ rid, const int* __restrict__ eid,
    const int* __restrict__ n2o,
    const float* __restrict__ ea, const float* __restrict__ er, const float* __restrict__ ee,
    const float* __restrict__ Win, const float* __restrict__ Wq, const float* __restrict__ Wk,
    const float* __restrict__ Wv,
    float* __restrict__ sg, float* __restrict__ qout, float* __restrict__ kout,
    float* __restrict__ vfout)
{
    __shared__ __align__(16) float sS[ATB*LDA];
    __shared__ __align__(16) float sH[ATB*LDA];
    __shared__ __align__(16) float sW[4096];
    const int tid = threadIdx.x;
    const int a0 = blockIdx.x*ATB;
    const int gi = tid>>4, gj = tid&15;
    const int lrow = tid>>3, lsub = tid&7;

    auto stageW = [&](const float* W) {
        const float4* src = (const float4*)W; float4* dst = (float4*)sW;
        #pragma unroll
        for (int r = 0; r < 4; ++r) dst[tid + 256*r] = src[tid + 256*r];
    };
    auto do_gemm = [&](const float* sA, float4& c0, float4& c1) {
        const float* a0p = sA + gi*LDA;
        const float* a1p = sA + (gi+16)*LDA;
        const float* wr  = sW + gj*4;
        #pragma unroll 8
        for (int k = 0; k < 64; ++k) {
            float av0 = a0p[k], av1 = a1p[k];
            float4 w = *(const float4*)(wr + k*64);
            c0.x = fmaf(av0,w.x,c0.x); c0.y = fmaf(av0,w.y,c0.y);
            c0.z = fmaf(av0,w.z,c0.z); c0.w = fmaf(av0,w.w,c0.w);
            c1.x = fmaf(av1,w.x,c1.x); c1.y = fmaf(av1,w.y,c1.y);
            c1.z = fmaf(av1,w.z,c1.z); c1.w = fmaf(av1,w.w,c1.w);
        }
    };
    auto do_ln = [&](const float* src, float* dst) {
        const float* sp = src + lrow*LDA + lsub*8;
        float v[8]; float s1 = 0.f;
        #pragma unroll
        for (int e = 0; e < 8; ++e) { v[e] = sp[e]; s1 += v[e]; }
        s1 += __shfl_xor(s1,1); s1 += __shfl_xor(s1,2); s1 += __shfl_xor(s1,4);
        float mean = s1*(1.0f/64.0f);
        float s2 = 0.f;
        #pragma unroll
        for (int e = 0; e < 8; ++e) { float t = v[e]-mean; s2 += t*t; }
        s2 += __shfl_xor(s2,1); s2 += __shfl_xor(s2,2); s2 += __shfl_xor(s2,4);
        float sc = 1.0f/sqrtf(s2*(1.0f/64.0f)+1e-5f);
        float* dp = dst + lrow*LDA + lsub*8;
        #pragma unroll
        for (int e = 0; e < 8; ++e) dp[e] = (v[e]-mean)*sc;
    };
    auto store_g = [&](float* base, float4 c0, float4 c1) {
        int g0 = a0+gi, g1 = a0+gi+16;
        if (g0 < NN) *(float4*)(base + (size_t)g0*64 + gj*4) = c0;
        if (g1 < NN) *(float4*)(base + (size_t)g1*64 + gj*4) = c1;
    };

    {   // feat -> sH  (overlapped with Win staging; both guarded by next sync)
        int ga = a0 + lrow;
        int io = (ga < NN) ? n2o[ga] : 0;
        #pragma unroll
        for (int e = 0; e < 8; ++e) {
            int c = lsub*8 + e;
            float x = 0.f;
            if (ga < NN) {
                if (c < 32)      x = ea[aid[io]*32 + c];
                else if (c < 48) x = er[rid[io]*16 + (c-32)];
                else             x = ee[eid[io]*16 + (c-48)];
            }
            sH[lrow*LDA + c] = x;
        }
    }
    stageW(Win);
    __syncthreads();
    {
        float4 c0 = make_float4(0,0,0,0), c1 = c0;
        do_gemm(sH, c0, c1);
        *(float4*)(sS + gi*LDA + gj*4)      = c0;
        *(float4*)(sS + (gi+16)*LDA + gj*4) = c1;
        store_g(sg, c0, c1);
    }
    __syncthreads();                 // all done with sH(feat), sW(Win); sS written
    do_ln(sS, sH);                   // overlap LN with Wk staging
    stageW(Wk);
    __syncthreads();
    { float4 c0 = make_float4(0,0,0,0), c1 = c0; do_gemm(sH, c0, c1); store_g(kout, c0, c1); }
    __syncthreads();
    stageW(Wv); __syncthreads();
    { float4 c0 = make_float4(0,0,0,0), c1 = c0; do_gemm(sH, c0, c1); store_g(vfout, c0, c1); }
    __syncthreads();
    stageW(Wq); __syncthreads();
    { float4 c0 = make_float4(0,0,0,0), c1 = c0; do_gemm(sH, c0, c1); store_g(qout, c0, c1); }
}

// ---------------- fused layer kernel: round-6 = round-0 arithmetic, 9 barriers ----------------
// Round-6: layer time proved insensitive to occupancy/spill/engine; the untouched
// structural cost is the 19-barrier lockstep chain with weight staging serialized
// through the single sW buffer. sM (16.9KB) and sVA (26KB) are dead in specific
// phases -> used as secondary weight buffers so each phase stages 2-3 weights at
// once and GEMMs run back-to-back. 9 barriers/layer. Cover-set of each barrier
// is annotated; arithmetic is byte-identical to round-0.
__global__ __launch_bounds__(256) void layer_kernel(
    const float* __restrict__ qin, const float* __restrict__ kin, const float* __restrict__ vfin,
    float* __restrict__ qout, float* __restrict__ kout, float* __restrict__ vfout,
    const float* __restrict__ vin, float* __restrict__ vout,
    float* __restrict__ sg, const float* __restrict__ dirn,
    const int* __restrict__ nbr, const int* __restrict__ bins,
    float* __restrict__ resb, const int* __restrict__ ridx, const int* __restrict__ n2o,
    const float* __restrict__ Wvec, const float* __restrict__ wdir,
    const float* __restrict__ dist_bias,
    const float* __restrict__ Wo, const float* __restrict__ W1, const float* __restrict__ W2,
    const float* __restrict__ Wg, const float* __restrict__ Wq, const float* __restrict__ Wk,
    const float* __restrict__ Wv, int l)
{
    __shared__ __align__(16) float sS[ATB*LDA];
    __shared__ __align__(16) float sH[ATB*LDA];
    __shared__ __align__(16) float sM[ATB*LDU];       // msg | weight buf B (4224 >= 4096)
    __shared__ __align__(16) float sVA[3][ATB*LDA];   // vec agg | FFN mids | weight buf C (6528 >= 4096)
    __shared__ __align__(16) float sW[4096];          // weight buf A
    __shared__ float sDS[ATB*24];

    const int tid = threadIdx.x;
    const int bswz = (blockIdx.x & 7) * (NBLK/8) + (blockIdx.x >> 3);
    const int a0 = bswz*ATB;
    const int gi = tid>>4, gj = tid&15;
    const int lrow = tid>>3, lsub = tid&7;
    const int wv = tid>>6, lane = tid&63;

    const float* Wo_l = Wo + l*4096;
    const float* Wg_l = Wg + l*4096;
    const float* Wc_l = Wvec + l*4096;
    const float* W1_l = W1 + l*8192;
    const float* W2_l = W2 + l*8192;
    const float* db_l = dist_bias + l*BINS*8;
    const float* wd_l = wdir + l*64;

    auto stageW = [&](const float* W, float* dst4) {
        const float4* src = (const float4*)W; float4* dst = (float4*)dst4;
        #pragma unroll
        for (int r = 0; r < 4; ++r) dst[tid + 256*r] = src[tid + 256*r];
    };
    auto stageW1h = [&](const float* W1l, int h, float* dst4) {
        const float4* src = (const float4*)W1l; float4* dst = (float4*)dst4;
        #pragma unroll
        for (int r = 0; r < 4; ++r) {
            int q = tid + 256*r;
            int row = q >> 4, c4i = q & 15;
            dst[q] = src[row*32 + h*16 + c4i];
        }
    };
    auto do_gemm = [&](const float* sA, int lda, const float* sWb, float4& c0, float4& c1) {
        const float* a0p = sA + gi*lda;
        const float* a1p = sA + (gi+16)*lda;
        const float* wr  = sWb + gj*4;
        #pragma unroll 8
        for (int k = 0; k < 64; ++k) {
            float av0 = a0p[k], av1 = a1p[k];
            float4 w = *(const float4*)(wr + k*64);
            c0.x = fmaf(av0,w.x,c0.x); c0.y = fmaf(av0,w.y,c0.y);
            c0.z = fmaf(av0,w.z,c0.z); c0.w = fmaf(av0,w.w,c0.w);
            c1.x = fmaf(av1,w.x,c1.x); c1.y = fmaf(av1,w.y,c1.y);
            c1.z = fmaf(av1,w.z,c1.z); c1.w = fmaf(av1,w.w,c1.w);
        }
    };
    auto do_ln = [&](const float* src, float* dst) {
        const float* sp = src + lrow*LDA + lsub*8;
        float v[8]; float s1 = 0.f;
        #pragma unroll
        for (int e = 0; e < 8; ++e) { v[e] = sp[e]; s1 += v[e]; }
        s1 += __shfl_xor(s1,1); s1 += __shfl_xor(s1,2); s1 += __shfl_xor(s1,4);
        float mean = s1*(1.0f/64.0f);
        float s2 = 0.f;
        #pragma unroll
        for (int e = 0; e < 8; ++e) { float t = v[e]-mean; s2 += t*t; }
        s2 += __shfl_xor(s2,1); s2 += __shfl_xor(s2,2); s2 += __shfl_xor(s2,4);
        float sc = 1.0f/sqrtf(s2*(1.0f/64.0f)+1e-5f);
        float* dp = dst + lrow*LDA + lsub*8;
        #pragma unroll
        for (int e = 0; e < 8; ++e) dp[e] = (v[e]-mean)*sc;
    };
    auto store_g = [&](float* base, float4 c0, float4 c1) {
        int g0 = a0+gi, g1 = a0+gi+16;
        if (g0 < NN) *(float4*)(base + (size_t)g0*64 + gj*4) = c0;
        if (g1 < NN) *(float4*)(base + (size_t)g1*64 + gj*4) = c1;
    };

    // ---- P0: load s ----
    {
        int ga = a0 + lrow;
        float4 z = make_float4(0,0,0,0);
        float4 x0 = z, x1 = z;
        if (ga < NN) {
            const float4* sp = (const float4*)(sg + (size_t)ga*64);
            x0 = sp[lsub*2]; x1 = sp[lsub*2+1];
        }
        float4* dp = (float4*)(sS + lrow*LDA);
        dp[lsub*2] = x0; dp[lsub*2+1] = x1;
    }
    stageW(Wo_l, sW);   // sW idle during attention; guarded by barrier 1

    // ---- P1: attention ----
    for (int aa = 0; aa < 8; ++aa) {
        int la = wv*8 + aa;
        int ga = a0 + la;
        if (ga >= NN) break;
        float qh = qin[(size_t)ga*64 + lane];
        float lg[KNB]; int nb[KNB];
        #pragma unroll
        for (int k = 0; k < KNB; ++k) {
            int j = nbr[ga*KNB + k];
            nb[k] = j;
            float t = qh * kin[(size_t)j*64 + lane];
            t += __shfl_xor(t,1); t += __shfl_xor(t,2); t += __shfl_xor(t,4);
            lg[k] = t*0.35355339059327373f + db_l[bins[ga*KNB+k]*8 + (lane>>3)];
        }
        float m = lg[0];
        #pragma unroll
        for (int k = 1; k < KNB; ++k) m = fmaxf(m, lg[k]);
        float ssum = 0.f;
        #pragma unroll
        for (int k = 0; k < KNB; ++k) { lg[k] = expf(lg[k]-m); ssum += lg[k]; }
        float inv = 1.0f/ssum;
        float mh=0.f, b0=0.f, b1=0.f, b2=0.f, s0=0.f, s1=0.f, s2=0.f;
        if (l > 0) {
            #pragma unroll
            for (int k = 0; k < KNB; ++k) {
                float w = lg[k]*inv; int j = nb[k];
                mh += w * vfin[(size_t)j*64 + lane];
                b0 += w * vin[(size_t)j*64 + lane];
                b1 += w * vin[(size_t)N64 + (size_t)j*64 + lane];
                b2 += w * vin[2*(size_t)N64 + (size_t)j*64 + lane];
                s0 += w * dirn[ga*48 + k*3 + 0];
                s1 += w * dirn[ga*48 + k*3 + 1];
                s2 += w * dirn[ga*48 + k*3 + 2];
            }
            sVA[0][la*LDA + lane] = b0;
            sVA[1][la*LDA + lane] = b1;
            sVA[2][la*LDA + lane] = b2;
        } else {
            #pragma unroll
            for (int k = 0; k < KNB; ++k) {
                float w = lg[k]*inv; int j = nb[k];
                mh += w * vfin[(size_t)j*64 + lane];
                s0 += w * dirn[ga*48 + k*3 + 0];
                s1 += w * dirn[ga*48 + k*3 + 1];
                s2 += w * dirn[ga*48 + k*3 + 2];
            }
        }
        sM[la*LDU + lane] = mh;
        if ((lane & 7) == 0) {
            int hh = lane >> 3;
            sDS[la*24 + 0*8 + hh] = s0;
            sDS[la*24 + 1*8 + hh] = s1;
            sDS[la*24 + 2*8 + hh] = s2;
        }
    }
    __syncthreads();   // B1: P0 sS + attention sM/sVA/sDS + Wo staged

    // ---- P2: s += msg @ Wo ----
    {
        float4 c0 = *(float4*)(sS + gi*LDA + gj*4);
        float4 c1 = *(float4*)(sS + (gi+16)*LDA + gj*4);
        do_gemm(sM, LDU, sW, c0, c1);
        *(float4*)(sS + gi*LDA + gj*4)      = c0;
        *(float4*)(sS + (gi+16)*LDA + gj*4) = c1;
    }
    __syncthreads();   // B2: sS stable; done reading sM(msg), sW(Wo)

    // ---- P3: LN -> sH ; stage Wg->sW AND Wvec->sM ----
    do_ln(sS, sH);
    stageW(Wg_l, sW);
    stageW(Wc_l, sM);
    __syncthreads();   // B3: sH + Wg + Wc visible

    // ---- P4: gate + vector update (no internal barriers) ----
    {
        float4 g0 = make_float4(0,0,0,0), g1 = g0;
        do_gemm(sH, LDA, sW, g0, g1);
        g0.x=sigmoid_f(g0.x); g0.y=sigmoid_f(g0.y); g0.z=sigmoid_f(g0.z); g0.w=sigmoid_f(g0.w);
        g1.x=sigmoid_f(g1.x); g1.y=sigmoid_f(g1.y); g1.z=sigmoid_f(g1.z); g1.w=sigmoid_f(g1.w);
        float4 wd4 = *(const float4*)&wd_l[gj*4];
        int g0i = a0+gi, g1i = a0+gi+16;
        #pragma unroll
        for (int p = 0; p < 3; ++p) {
            float4 t0 = make_float4(0,0,0,0), t1 = t0;
            if (l > 0) do_gemm(sVA[p], LDA, sM, t0, t1);
            float sp0 = sDS[gi*24 + p*8 + (gj>>1)];
            float sp1 = sDS[(gi+16)*24 + p*8 + (gj>>1)];
            if (g0i < NN) {
                float4 vi = make_float4(0,0,0,0);
                if (l > 0) vi = *(const float4*)(vin + (size_t)p*N64 + (size_t)g0i*64 + gj*4);
                float4 o;
                o.x = (vi.x + t0.x + wd4.x*sp0)*g0.x;
                o.y = (vi.y + t0.y + wd4.y*sp0)*g0.y;
                o.z = (vi.z + t0.z + wd4.z*sp0)*g0.z;
                o.w = (vi.w + t0.w + wd4.w*sp0)*g0.w;
                *(float4*)(vout + (size_t)p*N64 + (size_t)g0i*64 + gj*4) = o;
            }
            if (g1i < NN) {
                float4 vi = make_float4(0,0,0,0);
                if (l > 0) vi = *(const float4*)(vin + (size_t)p*N64 + (size_t)g1i*64 + gj*4);
                float4 o;
                o.x = (vi.x + t1.x + wd4.x*sp1)*g1.x;
                o.y = (vi.y + t1.y + wd4.y*sp1)*g1.y;
                o.z = (vi.z + t1.z + wd4.z*sp1)*g1.z;
                o.w = (vi.w + t1.w + wd4.w*sp1)*g1.w;
                *(float4*)(vout + (size_t)p*N64 + (size_t)g1i*64 + gj*4) = o;
            }
        }
    }
    __syncthreads();   // B4: done reading sW(Wg), sM(Wc), sVA, sDS (sH still live for P5)

    // ---- P5: FFN, both halves staged at once; mids in sVA[0]/sVA[1] ----
    stageW1h(W1_l, 0, sW);
    stageW1h(W1_l, 1, sM);
    __syncthreads();   // B5: W1 halves visible
    float4 u0a, u1a, u0b, u1b;
    {
        float4 c0 = make_float4(0,0,0,0), c1 = c0;
        do_gemm(sH, LDA, sW, c0, c1);
        u0a.x=gelu_f(c0.x); u0a.y=gelu_f(c0.y); u0a.z=gelu_f(c0.z); u0a.w=gelu_f(c0.w);
        u1a.x=gelu_f(c1.x); u1a.y=gelu_f(c1.y); u1a.z=gelu_f(c1.z); u1a.w=gelu_f(c1.w);
    }
    {
        float4 c0 = make_float4(0,0,0,0), c1 = c0;
        do_gemm(sH, LDA, sM, c0, c1);
        u0b.x=gelu_f(c0.x); u0b.y=gelu_f(c0.y); u0b.z=gelu_f(c0.z); u0b.w=gelu_f(c0.w);
        u1b.x=gelu_f(c1.x); u1b.y=gelu_f(c1.y); u1b.z=gelu_f(c1.z); u1b.w=gelu_f(c1.w);
    }
    // mids -> sVA planes (sVA free after B4; writes race nothing: sW/sM only read)
    *(float4*)(sVA[0] + gi*LDA + gj*4)      = u0a;
    *(float4*)(sVA[0] + (gi+16)*LDA + gj*4) = u1a;
    *(float4*)(sVA[1] + gi*LDA + gj*4)      = u0b;
    *(float4*)(sVA[1] + (gi+16)*LDA + gj*4) = u1b;
    __syncthreads();   // B6: mids visible; done reading sW/sM(W1)
    stageW(W2_l, sW);
    stageW(W2_l + 4096, sM);
    __syncthreads();   // B7: W2 halves visible
    {
        float4 c0 = *(float4*)(sS + gi*LDA + gj*4);
        float4 c1 = *(float4*)(sS + (gi+16)*LDA + gj*4);
        do_gemm(sVA[0], LDA, sW, c0, c1);
        do_gemm(sVA[1], LDA, sM, c0, c1);
        *(float4*)(sS + gi*LDA + gj*4)      = c0;
        *(float4*)(sS + (gi+16)*LDA + gj*4) = c1;
    }
    __syncthreads();   // B8: sS stable; done reading sW/sM(W2), sVA(mids)

    // ---- P6: next-layer q/k/vf (single staged phase) or pooling ----
    if (l < LAYERS-1) {
        do_ln(sS, sH);                       // sH last read before B6 -> safe
        stageW(Wk + (l+1)*4096, sW);
        stageW(Wv + (l+1)*4096, sM);
        stageW(Wq + (l+1)*4096, (float*)sVA);
        __syncthreads();   // B9: sH + Wk/Wv/Wq visible
        { float4 c0 = make_float4(0,0,0,0), c1 = c0; do_gemm(sH, LDA, sW, c0, c1); store_g(kout, c0, c1); }
        { float4 c0 = make_float4(0,0,0,0), c1 = c0; do_gemm(sH, LDA, sM, c0, c1); store_g(vfout, c0, c1); }
        { float4 c0 = make_float4(0,0,0,0), c1 = c0; do_gemm(sH, LDA, (const float*)sVA, c0, c1); store_g(qout, c0, c1); }
        {
            int ga = a0 + lrow;
            if (ga < NN) {
                float4* dp = (float4*)(sg + (size_t)ga*64);
                const float4* sp = (const float4*)(sS + lrow*LDA);
                dp[lsub*2] = sp[lsub*2]; dp[lsub*2+1] = sp[lsub*2+1];
            }
        }
    } else {
        int ga = a0 + lrow;
        if (ga < NN) {
            int r = ridx[n2o[ga]];
            #pragma unroll
            for (int e = 0; e < 8; ++e)
                atomicAdd(&resb[r*64 + lsub*8 + e], sS[lrow*LDA + lsub*8 + e]);
        }
    }
}

// ---------------- head ----------------
__global__ void head_kernel(const float* __restrict__ res, const float* __restrict__ Wout,
                            const float* __restrict__ bout, float* __restrict__ out, int r_total) {
    int wave = threadIdx.x >> 6, lane = threadIdx.x & 63;
    int r = blockIdx.x*4 + wave;
    if (r >= r_total) return;
    float p = res[r*HID + lane] * (1.0f/APR);
    float o0 = p * Wout[lane*2 + 0];
    float o1 = p * Wout[lane*2 + 1];
    #pragma unroll
    for (int off = 1; off < 64; off <<= 1) { o0 += __shfl_xor(o0, off); o1 += __shfl_xor(o1, off); }
    if (lane == 0) { out[r*2+0] = o0 + bout[0]; out[r*2+1] = o1 + bout[1]; }
}

// ---------------- launcher ----------------
extern "C" void kernel_launch(void* const* d_in, const int* in_sizes, int n_in,
                              void* d_out, int out_size, void* d_ws, size_t ws_size,
                              hipStream_t stream) {
    const float* coords    = (const float*)d_in[0];
    const int*   atom_ids  = (const int*)d_in[1];
    const int*   res_ids   = (const int*)d_in[2];
    const int*   elem_ids  = (const int*)d_in[3];
    const int*   ridx      = (const int*)d_in[4];
    const float* emb_atom  = (const float*)d_in[5];
    const float* emb_res   = (const float*)d_in[6];
    const float* emb_elem  = (const float*)d_in[7];
    const float* Win       = (const float*)d_in[8];
    const float* Wq        = (const float*)d_in[9];
    const float* Wk        = (const float*)d_in[10];
    const float* Wv        = (const float*)d_in[11];
    const float* Wvec      = (const float*)d_in[12];
    const float* wdir      = (const float*)d_in[13];
    const float* dist_bias = (const float*)d_in[14];
    const float* Wo        = (const float*)d_in[15];
    const float* W1        = (const float*)d_in[16];
    const float* W2        = (const float*)d_in[17];
    const float* Wg        = (const float*)d_in[18];
    const float* Wout      = (const float*)d_in[19];
    const float* bout      = (const float*)d_in[20];
    float* out = (float*)d_out;

    float* ws = (float*)d_ws;
    float* qA = ws + OFF_QA;  float* kA = ws + OFF_KA;  float* fA = ws + OFF_FA;
    float* qB = ws + OFF_QB;  float* kB = ws + OFF_KB;  float* fB = ws + OFF_FB;
    float* vA = ws + OFF_VA;  float* vB = ws + OFF_VB;
    float* sg = ws + OFF_S;
    float* dirn_s = ws + OFF_DIRNS;
    float4* c4  = (float4*)(ws + OFF_C4);
    float4* c4s = (float4*)(ws + OFF_C4S);
    float* resb = ws + OFF_RES;
    int* nbr_s  = (int*)(ws + OFF_NBRS);
    int* bins_s = (int*)(ws + OFF_BINSS);
    int* o2n    = (int*)(ws + OFF_O2N);
    int* n2o    = (int*)(ws + OFF_N2O);
    int* cellid = (int*)(ws + OFF_CELL);
    int* hist   = (int*)(ws + OFF_HIST);
    int* cnt    = (int*)(ws + OFF_CNT);
    int* baseb  = (int*)(ws + OFF_BASE);

    hipMemsetAsync(hist, 0, 2*4096*sizeof(int), stream);

    pad_cell_kernel<<<(NN+255)/256, 256, 0, stream>>>(coords, c4, cellid, hist, resb, NN);
    scan_kernel<<<1, 256, 0, stream>>>(hist, baseb);
    scatter_kernel<<<(NN+255)/256, 256, 0, stream>>>(cellid, baseb, cnt, o2n, n2o, c4, c4s, NN);
    knn_grid_kernel<<<(NN+3)/4, 256, 0, stream>>>(c4s, baseb, hist, n2o, o2n, nbr_s, bins_s, dirn_s, NN);

    prologue_kernel<<<NBLK, 256, 0, stream>>>(atom_ids, res_ids, elem_ids, n2o,
                                              emb_atom, emb_res, emb_elem,
                                              Win, Wq, Wk, Wv, sg, qA, kA, fA);
    for (int l = 0; l < LAYERS; ++l) {
        int p = l & 1;
        const float* qin = p ? qB : qA;  float* qout = p ? qA : qB;
        const float* kin = p ? kB : kA;  float* kout = p ? kA : kB;
        const float* fin = p ? fB : fA;  float* fout = p ? fA : fB;
        const float* vin = p ? vB : vA;  float* vout = p ? vA : vB;
        layer_kernel<<<NBLK, 256, 0, stream>>>(qin, kin, fin, qout, kout, fout,
                                               vin, vout, sg, dirn_s, nbr_s, bins_s,
                                               resb, ridx, n2o,
                                               Wvec, wdir, dist_bias,
                                               Wo, W1, W2, Wg, Wq, Wk, Wv, l);
    }
    head_kernel<<<(RR+3)/4, 256, 0, stream>>>(resb, Wout, bout, out, RR);
}